// Round 3
// baseline (1158.427 us; speedup 1.0000x reference)
//
#include <hip/hip_runtime.h>

// Problem constants (match reference)
#define NHEAD   16
#define DK      64
#define DMODEL  1024
#define BSZ     2
#define SEQLEN  1024
#define NI      64
#define NN2     1088          // SEQLEN + NI
#define NBUCK   9             // N_B + 1
#define TOPK    16

#define T_ITEM  (BSZ*SEQLEN)  // 2048 item tokens
#define T_INT   (BSZ*NN2)     // 2176 intent tokens

// workspace layout (bytes). total ~26.4 MB
#define Q_OFF   ((size_t)0)                          // q: 2048x1024 f32
#define K_OFF   (Q_OFF + (size_t)T_ITEM*DMODEL*4)    // k: 2176x1024 f32
#define V_OFF   (K_OFF + (size_t)T_INT*DMODEL*4)     // v: 2176x1024 f32
#define CNT_OFF (V_OFF + (size_t)T_INT*DMODEL*4)     // counts: 18 ints
#define LI_OFF  (CNT_OFF + 128)                      // item lists 9x2048
#define LN_OFF  (LI_OFF + (size_t)NBUCK*T_ITEM*4)    // intent lists 9x2176
#define WS_NEED (LN_OFF + (size_t)NBUCK*T_INT*4)

// fp64 sidecar buffers live INSIDE the V region (used before v-GEMM writes it):
//   q0d: 2048*64 f64 row-major (1 MB), k0dT: 64 x 2176 f64 TRANSPOSED (1.1 MB)
#define Q0D_OFF V_OFF
#define K0D_OFF (V_OFF + (size_t)T_ITEM*64*8)

#define X_OUT_ELEMS ((size_t)BSZ*SEQLEN*DMODEL)      // 2,097,152
#define SIDX_ELEMS  ((size_t)BSZ*SEQLEN)             // 2048

__device__ __forceinline__ int clampi(int v, int lo, int hi) {
  return v < lo ? lo : (v > hi ? hi : v);
}

// ---------------------------------------------------------------------------
// Kernel 1: counting-sort tokens into buckets (order within bucket irrelevant)
// ---------------------------------------------------------------------------
__global__ void bucketize_kernel(const int* __restrict__ b_seq, const int* __restrict__ b_seq2,
                                 int* __restrict__ cnt, int* __restrict__ list_item,
                                 int* __restrict__ list_int) {
  int t = blockIdx.x * blockDim.x + threadIdx.x;
  if (t < T_ITEM) {
    int B = clampi(b_seq[t], 0, NBUCK - 1);
    int p = atomicAdd(&cnt[B], 1);
    if (p >= 0 && p < T_ITEM) list_item[B * T_ITEM + p] = t;
  }
  if (t < T_INT) {
    int B = clampi(b_seq2[t], 0, NBUCK - 1);
    int p = atomicAdd(&cnt[NBUCK + B], 1);
    if (p >= 0 && p < T_INT) list_int[B * T_INT + p] = t;
  }
}

// ---------------------------------------------------------------------------
// fp64 sidecar A: head-0 projection  Y[tok][k] = sum_d X[tok][d]*W[B][d][k]
// transposed=0: Y[tok*64 + k] (row-major, for Q0)
// transposed=1: Y[k*T + tok]  (k-major, so argmax reads are lane-coalesced)
// ---------------------------------------------------------------------------
__global__ __launch_bounds__(256) void proj_head0_f64(
    const float* __restrict__ X, const float* __restrict__ W,
    const int* __restrict__ bseq, double* __restrict__ Y, const int T,
    const int transposed) {
  const int wave = (int)threadIdx.x >> 6, lane = (int)threadIdx.x & 63;
  const int tok = blockIdx.x * 4 + wave;
  if (tok >= T) return;
  const int B = clampi(bseq[tok], 0, NBUCK - 1);
  const float* xr = X + (size_t)tok * DMODEL;
  const float* wb = W + (size_t)B * DMODEL * (NHEAD * DK) + lane;  // W[B][d][lane]
  double acc = 0.0;
  #pragma unroll 4
  for (int d = 0; d < DMODEL; ++d)
    acc += (double)xr[d] * (double)wb[(size_t)d * (NHEAD * DK)];
  if (transposed) Y[(size_t)lane * T + tok] = acc;
  else            Y[(size_t)tok * 64 + lane] = acc;
}

// ---------------------------------------------------------------------------
// fp64 sidecar B: per q-row fp64 scores over all 1088 keys; exact
// first-occurrence argmax over [0,1024) -> sIdx and [1024,1088) -> aIdx.
// K0 is TRANSPOSED [64][T_INT]: inner k loop reads lanes-consecutive m ->
// fully coalesced loads.
// ---------------------------------------------------------------------------
__global__ __launch_bounds__(256) void argmax_f64(
    const double* __restrict__ Q0, const double* __restrict__ K0T,
    float* __restrict__ out_s, float* __restrict__ out_a) {
  const int n = blockIdx.x;          // b*1024 + nn
  const int b = n >> 10;
  const int t = (int)threadIdx.x;
  __shared__ double qs[64];
  __shared__ double bval[256];  __shared__ int bidx[256];
  __shared__ double bval2[256]; __shared__ int bidx2[256];
  if (t < 64) qs[t] = Q0[(size_t)n * 64 + t];
  __syncthreads();
  double v1 = -1e300; int i1 = 0x7FFFFFFF;
  double v2 = -1e300; int i2 = 0x7FFFFFFF;
  for (int m = t; m < NN2; m += 256) {
    const double* base = K0T + (size_t)b * NN2 + m;   // column m of K0T
    double s = 0.0;
    #pragma unroll 8
    for (int k = 0; k < 64; ++k) s += qs[k] * base[(size_t)k * T_INT];
    if (m < 1024) { if (s > v1 || (s == v1 && m < i1)) { v1 = s; i1 = m; } }
    else          { if (s > v2 || (s == v2 && m < i2)) { v2 = s; i2 = m; } }
  }
  bval[t] = v1; bidx[t] = i1; bval2[t] = v2; bidx2[t] = i2;
  __syncthreads();
  for (int off = 128; off >= 1; off >>= 1) {
    if (t < off) {
      if (bval[t+off] >  bval[t] || (bval[t+off] ==  bval[t] &&  bidx[t+off] <  bidx[t])) { bval[t]  = bval[t+off];  bidx[t]  = bidx[t+off]; }
      if (bval2[t+off] > bval2[t] || (bval2[t+off] == bval2[t] && bidx2[t+off] < bidx2[t])) { bval2[t] = bval2[t+off]; bidx2[t] = bidx2[t+off]; }
    }
    __syncthreads();
  }
  if (t == 0) {
    out_s[n] = (float)bidx[0];
    out_a[n] = (float)(bidx2[0] - 1024);
  }
}

// ---------------------------------------------------------------------------
// Kernel 2: FUSED grouped GEMM for q,k,v in one launch.
// blockIdx.z = g*9 + bucket, g=0:q(item,W_item) 1:k(intent,W_int[0]) 2:v(W_int[1])
// Tile 128x128, BK=16, 256 threads, 8x8 micro-tile.
// LDS-pipe relief: only W staged in LDS; X fragments read per-thread from
// global (16 lanes/address -> broadcast coalesce, L1/L2-hit).
// Per-output FMA order (k ascending) identical to previous -> bitwise same.
// ---------------------------------------------------------------------------
#define GTM 128
#define GTN 128
#define GBK 16

__global__ __launch_bounds__(256, 3) void gemm_grouped_fused(
    const float* __restrict__ item, const float* __restrict__ intent,
    const float* __restrict__ Wq, const float* __restrict__ Wk,
    const float* __restrict__ Wv,
    const int* __restrict__ list_item, const int* __restrict__ list_int,
    const int* __restrict__ cnt,
    float* __restrict__ qb, float* __restrict__ kb, float* __restrict__ vb) {
  const int z = blockIdx.z;
  const int g = z / 9, B = z - g * 9;
  const float* X;  const float* W;  const int* list;  float* Y;  int n, Tmax;
  if (g == 0) { X = item;   W = Wq; list = list_item; Y = qb; n = min(cnt[B], T_ITEM);         Tmax = T_ITEM; }
  else if (g == 1) { X = intent; W = Wk; list = list_int;  Y = kb; n = min(cnt[NBUCK + B], T_INT); Tmax = T_INT; }
  else { X = intent; W = Wv; list = list_int;  Y = vb; n = min(cnt[NBUCK + B], T_INT); Tmax = T_INT; }

  const int row0 = blockIdx.y * GTM;
  if (row0 >= n) return;                 // uniform across block
  const int rows = min(GTM, n - row0);
  const int c0 = blockIdx.x * GTN;
  const int t = (int)threadIdx.x;

  __shared__ float Ws[GBK][GTN + 4];

  const int ty = t >> 4;              // 0..15 -> rows ty*8..+7
  const int tx = t & 15;              // 0..15 -> cols tx*8..+7

  // my 8 row pointers (gathered once)
  const float* xr[8];
  int toks[8];
  #pragma unroll
  for (int i = 0; i < 8; ++i) {
    const int rr = ty * 8 + i;
    toks[i] = clampi(list[row0 + min(rr, rows - 1)], 0, Tmax - 1);
    xr[i] = X + (size_t)toks[i] * DMODEL;
  }

  const int kW = t >> 4;              // 0..15
  const int cW = (t & 15) * 8;        // 0..120

  float acc[8][8];
  #pragma unroll
  for (int i = 0; i < 8; ++i)
    #pragma unroll
    for (int j = 0; j < 8; ++j) acc[i][j] = 0.f;

  for (int k0 = 0; k0 < DMODEL; k0 += GBK) {
    const float* wp = W + ((size_t)B * DMODEL + k0 + kW) * (size_t)(NHEAD * DK) + c0 + cW;
    const float4 wa = *(const float4*)wp;
    const float4 wb = *(const float4*)(wp + 4);
    __syncthreads();                        // previous tile fully consumed
    *(float4*)&Ws[kW][cW]     = wa;
    *(float4*)&Ws[kW][cW + 4] = wb;
    __syncthreads();

    #pragma unroll
    for (int kq = 0; kq < GBK; kq += 4) {
      float4 xa[8];
      #pragma unroll
      for (int i = 0; i < 8; ++i) xa[i] = *(const float4*)(xr[i] + k0 + kq);
      #pragma unroll
      for (int u = 0; u < 4; ++u) {
        float bv[8];
        *(float4*)&bv[0] = *(const float4*)&Ws[kq + u][tx * 8];
        *(float4*)&bv[4] = *(const float4*)&Ws[kq + u][tx * 8 + 4];
        #pragma unroll
        for (int i = 0; i < 8; ++i) {
          const float av = (u == 0) ? xa[i].x : (u == 1) ? xa[i].y : (u == 2) ? xa[i].z : xa[i].w;
          #pragma unroll
          for (int j = 0; j < 8; ++j)
            acc[i][j] = fmaf(av, bv[j], acc[i][j]);
        }
      }
    }
  }

  #pragma unroll
  for (int i = 0; i < 8; ++i) {
    const int r = ty * 8 + i;
    if (r < rows) {
      float* yr = Y + (size_t)toks[i] * (size_t)(NHEAD * DK) + c0 + tx * 8;
      *(float4*)yr       = make_float4(acc[i][0], acc[i][1], acc[i][2], acc[i][3]);
      *(float4*)(yr + 4) = make_float4(acc[i][4], acc[i][5], acc[i][6], acc[i][7]);
    }
  }
}

// ---------------------------------------------------------------------------
// Kernel 3: fused attention: scores -> softmax -> exact top-16 per segment ->
//           sparse p@V.  (index outputs come from the fp64 sidecar)
// Block = 256 thr (4 waves), 16 q-rows per block (4 per wave).
//
// LDS-pipe relief vs previous: q operands read via WAVE-UNIFORM global loads
// (scalarized to s_load / SMEM pipe, or VMEM broadcast) instead of 1088
// ds_read_b128 per wave. K staging unchanged. Arithmetic order unchanged ->
// bitwise-identical output.
// ---------------------------------------------------------------------------
__device__ __forceinline__ unsigned ordf(float v) {
  unsigned s = __float_as_uint(v);
  return s ^ ((unsigned)((int)s >> 31) | 0x80000000u);
}
__device__ __forceinline__ float unordf(unsigned u) {
  unsigned s = (u & 0x80000000u) ? (u ^ 0x80000000u) : ~u;
  return __uint_as_float(s);
}
__device__ __forceinline__ unsigned long long shfl_xor_u64(unsigned long long w, int off) {
  unsigned lo = __shfl_xor((unsigned)w, off);
  unsigned hi = __shfl_xor((unsigned)(w >> 32), off);
  return ((unsigned long long)hi << 32) | lo;
}

__global__ __launch_bounds__(256) void attn_kernel(
    const float* __restrict__ Q, const float* __restrict__ K,
    const float* __restrict__ V, float* __restrict__ outx) {
  const int b = blockIdx.z, h = blockIdx.y;
  const int n0 = blockIdx.x * 16;
  const int t = (int)threadIdx.x;
  const int wave = t >> 6, lane = t & 63;

  __shared__ float Ks[64][68];        // +4 pad: conflict-free b128
  __shared__ int   kept_m[16][32];
  __shared__ float kept_p[16][32];

  const int r0 = wave * 4;

  // wave-uniform q-row pointers (reads below scalarize: uniform address)
  const float* qrow[4];
  #pragma unroll
  for (int r = 0; r < 4; ++r)
    qrow[r] = Q + (size_t)(b * SEQLEN + n0 + r0 + r) * (NHEAD * DK) + h * DK;

  float sv[4][17];                    // static-indexed (unrolled loops only)

  #pragma unroll
  for (int c = 0; c < 17; ++c) {
    if (c > 0) __syncthreads();
    #pragma unroll
    for (int j = 0; j < 4; ++j) {
      const int row = (t >> 4) + 16 * j;
      const int k4 = (t & 15) * 4;
      *(float4*)&Ks[row][k4] =
          *(const float4*)(K + (size_t)(b * NN2 + c * 64 + row) * (NHEAD * DK) + h * DK + k4);
    }
    __syncthreads();

    float a0 = 0.f, a1 = 0.f, a2 = 0.f, a3 = 0.f;
    #pragma unroll 4
    for (int k4 = 0; k4 < 64; k4 += 4) {
      const float4 kv = *(const float4*)&Ks[lane][k4];
      const float4 q0 = *(const float4*)(qrow[0] + k4);   // uniform -> s_load
      const float4 q1 = *(const float4*)(qrow[1] + k4);
      const float4 q2 = *(const float4*)(qrow[2] + k4);
      const float4 q3 = *(const float4*)(qrow[3] + k4);
      a0 = fmaf(q0.x, kv.x, a0); a0 = fmaf(q0.y, kv.y, a0);
      a0 = fmaf(q0.z, kv.z, a0); a0 = fmaf(q0.w, kv.w, a0);
      a1 = fmaf(q1.x, kv.x, a1); a1 = fmaf(q1.y, kv.y, a1);
      a1 = fmaf(q1.z, kv.z, a1); a1 = fmaf(q1.w, kv.w, a1);
      a2 = fmaf(q2.x, kv.x, a2); a2 = fmaf(q2.y, kv.y, a2);
      a2 = fmaf(q2.z, kv.z, a2); a2 = fmaf(q2.w, kv.w, a2);
      a3 = fmaf(q3.x, kv.x, a3); a3 = fmaf(q3.y, kv.y, a3);
      a3 = fmaf(q3.z, kv.z, a3); a3 = fmaf(q3.w, kv.w, a3);
    }
    sv[0][c] = a0 * 0.125f; sv[1][c] = a1 * 0.125f;
    sv[2][c] = a2 * 0.125f; sv[3][c] = a3 * 0.125f;
  }

  // ---- softmax stats, 4 rows interleaved ----
  float M_[4], invL_[4];
  {
    float L_[4];
    #pragma unroll
    for (int r = 0; r < 4; ++r) {
      float M = -3.402823466e38f;
      #pragma unroll
      for (int c = 0; c < 17; ++c) M = fmaxf(M, sv[r][c]);
      M_[r] = M;
    }
    #pragma unroll
    for (int off = 32; off >= 1; off >>= 1) {
      #pragma unroll
      for (int r = 0; r < 4; ++r) M_[r] = fmaxf(M_[r], __shfl_xor(M_[r], off));
    }
    #pragma unroll
    for (int r = 0; r < 4; ++r) {
      float L = 0.f;
      #pragma unroll
      for (int c = 0; c < 17; ++c) L += __expf(sv[r][c] - M_[r]);
      L_[r] = L;
    }
    #pragma unroll
    for (int off = 32; off >= 1; off >>= 1) {
      #pragma unroll
      for (int r = 0; r < 4; ++r) L_[r] += __shfl_xor(L_[r], off);
    }
    #pragma unroll
    for (int r = 0; r < 4; ++r) invL_[r] = 1.0f / L_[r];
  }

  // ---- segment 1 keys + per-lane top-2 init ----
  unsigned kh[4][16];
  #pragma unroll
  for (int r = 0; r < 4; ++r)
    #pragma unroll
    for (int c = 0; c < 16; ++c) kh[r][c] = ordf(sv[r][c]);

  unsigned long long b1_[4], b2_[4];
  unsigned alive_[4];
  #pragma unroll
  for (int r = 0; r < 4; ++r) {
    unsigned long long b1 = 0ull, b2 = 0ull;
    #pragma unroll
    for (int c = 0; c < 16; ++c) {
      const unsigned long long k64 =
          ((unsigned long long)kh[r][c] << 32) | (unsigned)~(unsigned)(c * 64 + lane);
      const unsigned long long mn = (k64 < b1) ? k64 : b1;  // min(b1,k)
      b1 = (k64 > b1) ? k64 : b1;
      b2 = (mn > b2) ? mn : b2;
    }
    b1_[r] = b1; b2_[r] = b2; alive_[r] = 0xFFFFu;
  }

  // ---- segment 1: 16 extraction rounds, 4 rows interleaved ----
  for (int round = 0; round < TOPK; ++round) {
    unsigned long long w0 = b1_[0], w1 = b1_[1], w2 = b1_[2], w3 = b1_[3];
    #pragma unroll
    for (int off = 1; off < 64; off <<= 1) {
      unsigned long long o;
      o = shfl_xor_u64(w0, off); w0 = (o > w0) ? o : w0;
      o = shfl_xor_u64(w1, off); w1 = (o > w1) ? o : w1;
      o = shfl_xor_u64(w2, off); w2 = (o > w2) ? o : w2;
      o = shfl_xor_u64(w3, off); w3 = (o > w3) ? o : w3;
    }
    const unsigned long long ws[4] = {w0, w1, w2, w3};
    #pragma unroll
    for (int r = 0; r < 4; ++r) {
      const unsigned long long w = ws[r];
      const int m = (int)((~(unsigned)w) & 1023u);
      if (lane == round) {
        kept_m[r0 + r][round] = m;
        kept_p[r0 + r][round] = __expf(unordf((unsigned)(w >> 32)) - M_[r]) * invL_[r];
      }
      if ((m & 63) == lane) {          // winner lane bookkeeping
        alive_[r] &= ~(1u << (m >> 6));
        if (b2_[r]) { b1_[r] = b2_[r]; b2_[r] = 0ull; }
        else {
          unsigned long long mx = 0ull;
          #pragma unroll
          for (int c = 0; c < 16; ++c) {
            const unsigned long long k64 =
                ((unsigned long long)kh[r][c] << 32) | (unsigned)~(unsigned)(c * 64 + lane);
            if ((alive_[r] >> c) & 1u) mx = (k64 > mx) ? k64 : mx;
          }
          b1_[r] = mx;
        }
      }
    }
  }

  // ---- segment 2: bitonic sort (descending) of the 64 tail candidates ----
  {
    unsigned long long w_[4];
    #pragma unroll
    for (int r = 0; r < 4; ++r)
      w_[r] = ((unsigned long long)ordf(sv[r][16]) << 32) | (unsigned)~(unsigned)lane;
    #pragma unroll
    for (int k = 2; k <= 64; k <<= 1) {
      #pragma unroll
      for (int j = k >> 1; j >= 1; j >>= 1) {
        const bool tm = (((lane & j) != 0) == ((lane & k) != 0));
        #pragma unroll
        for (int r = 0; r < 4; ++r) {
          const unsigned long long o = shfl_xor_u64(w_[r], j);
          w_[r] = ((o > w_[r]) == tm) ? o : w_[r];
        }
      }
    }
    if (lane < TOPK) {
      #pragma unroll
      for (int r = 0; r < 4; ++r) {
        kept_m[r0 + r][TOPK + lane] = 1024 + (int)((~(unsigned)w_[r]) & 63u);
        kept_p[r0 + r][TOPK + lane] =
            __expf(unordf((unsigned)(w_[r] >> 32)) - M_[r]) * invL_[r];
      }
    }
  }
  __syncthreads();

  #pragma unroll
  for (int rr = 0; rr < 4; ++rr) {
    const int r_loc = wave * 4 + rr;
    const int n = n0 + r_loc;
    float x = 0.f;
    #pragma unroll
    for (int i = 0; i < 32; ++i) {
      const int m = clampi(kept_m[r_loc][i], 0, NN2 - 1);
      const float p = kept_p[r_loc][i];
      x = fmaf(p, V[(size_t)(b * NN2 + m) * (NHEAD * DK) + h * DK + lane], x);
    }
    outx[(size_t)(b * SEQLEN + n) * (NHEAD * DK) + h * DK + lane] = x;
  }
}

// ---------------------------------------------------------------------------
extern "C" void kernel_launch(void* const* d_in, const int* in_sizes, int n_in,
                              void* d_out, int out_size, void* d_ws, size_t ws_size,
                              hipStream_t stream) {
  const float* item    = (const float*)d_in[0];
  const float* intent  = (const float*)d_in[1];
  // d_in[2] = mask: constant all-True -> no-op, skipped
  const int*   b_seq   = (const int*)d_in[3];
  const int*   b_seq2  = (const int*)d_in[4];
  const float* W_item  = (const float*)d_in[5];   // [9][1024][16][64]
  const float* W_int   = (const float*)d_in[6];   // [2][9][1024][16][64]

  if (ws_size < WS_NEED) return;   // clean failure instead of device fault

  char* ws = (char*)d_ws;
  float* qb = (float*)(ws + Q_OFF);
  float* kb = (float*)(ws + K_OFF);
  float* vb = (float*)(ws + V_OFF);
  double* q0d = (double*)(ws + Q0D_OFF);   // aliases V region (used before v-GEMM)
  double* k0dT = (double*)(ws + K0D_OFF);  // transposed [64][T_INT]
  int* cnt       = (int*)(ws + CNT_OFF);
  int* list_item = (int*)(ws + LI_OFF);
  int* list_int  = (int*)(ws + LN_OFF);

  float* outx  = (float*)d_out;
  float* out_s = outx + X_OUT_ELEMS;
  float* out_a = out_s + SIDX_ELEMS;

  hipMemsetAsync(cnt, 0, 128, stream);
  bucketize_kernel<<<dim3(9), 256, 0, stream>>>(b_seq, b_seq2, cnt, list_item, list_int);

  // fp64 sidecar: head-0 q/k projections + exact argmax -> sIdx, aIdx.
  proj_head0_f64<<<dim3((T_ITEM + 3) / 4), 256, 0, stream>>>(item, W_item, b_seq, q0d, T_ITEM, 0);
  proj_head0_f64<<<dim3((T_INT + 3) / 4), 256, 0, stream>>>(intent, W_int, b_seq2, k0dT, T_INT, 1);
  argmax_f64<<<dim3(T_ITEM), 256, 0, stream>>>(q0d, k0dT, out_s, out_a);

  // fused fp32 q/k/v grouped GEMM (runs after argmax; v-write aliases sidecar)
  gemm_grouped_fused<<<dim3(8, 17, 27), 256, 0, stream>>>(
      item, intent,
      W_item, W_int, W_int + (size_t)NBUCK * DMODEL * (NHEAD * DK),
      list_item, list_int, cnt, qb, kb, vb);

  attn_kernel<<<dim3(SEQLEN / 16, NHEAD, BSZ), 256, 0, stream>>>(qb, kb, vb, outx);
}

// Round 4
// 938.772 us; speedup vs baseline: 1.2340x; 1.2340x over previous
//
#include <hip/hip_runtime.h>

// Problem constants (match reference)
#define NHEAD   16
#define DK      64
#define DMODEL  1024
#define BSZ     2
#define SEQLEN  1024
#define NI      64
#define NN2     1088          // SEQLEN + NI
#define NBUCK   9             // N_B + 1
#define TOPK    16

#define T_ITEM  (BSZ*SEQLEN)  // 2048 item tokens
#define T_INT   (BSZ*NN2)     // 2176 intent tokens

// workspace layout (bytes). total ~26.4 MB
#define Q_OFF   ((size_t)0)                          // q: 2048x1024 f32
#define K_OFF   (Q_OFF + (size_t)T_ITEM*DMODEL*4)    // k: 2176x1024 f32
#define V_OFF   (K_OFF + (size_t)T_INT*DMODEL*4)     // v: 2176x1024 f32
#define CNT_OFF (V_OFF + (size_t)T_INT*DMODEL*4)     // counts: 18 ints
#define LI_OFF  (CNT_OFF + 128)                      // item lists 9x2048
#define LN_OFF  (LI_OFF + (size_t)NBUCK*T_ITEM*4)    // intent lists 9x2176
#define WS_NEED (LN_OFF + (size_t)NBUCK*T_INT*4)

// fp64 sidecar buffers live INSIDE the V region (used before v-GEMM writes it):
//   q0d: 2048*64 f64 row-major (1 MB), k0dT: 64 x 2176 f64 TRANSPOSED (1.1 MB)
#define Q0D_OFF V_OFF
#define K0D_OFF (V_OFF + (size_t)T_ITEM*64*8)

#define X_OUT_ELEMS ((size_t)BSZ*SEQLEN*DMODEL)      // 2,097,152
#define SIDX_ELEMS  ((size_t)BSZ*SEQLEN)             // 2048

__device__ __forceinline__ int clampi(int v, int lo, int hi) {
  return v < lo ? lo : (v > hi ? hi : v);
}

// ---------------------------------------------------------------------------
// Kernel 1: counting-sort tokens into buckets (order within bucket irrelevant)
// ---------------------------------------------------------------------------
__global__ void bucketize_kernel(const int* __restrict__ b_seq, const int* __restrict__ b_seq2,
                                 int* __restrict__ cnt, int* __restrict__ list_item,
                                 int* __restrict__ list_int) {
  int t = blockIdx.x * blockDim.x + threadIdx.x;
  if (t < T_ITEM) {
    int B = clampi(b_seq[t], 0, NBUCK - 1);
    int p = atomicAdd(&cnt[B], 1);
    if (p >= 0 && p < T_ITEM) list_item[B * T_ITEM + p] = t;
  }
  if (t < T_INT) {
    int B = clampi(b_seq2[t], 0, NBUCK - 1);
    int p = atomicAdd(&cnt[NBUCK + B], 1);
    if (p >= 0 && p < T_INT) list_int[B * T_INT + p] = t;
  }
}

// ---------------------------------------------------------------------------
// fp64 sidecar A: head-0 projection  Y[tok][k] = sum_d X[tok][d]*W[B][d][k]
// transposed=0: Y[tok*64 + k] (row-major, for Q0)
// transposed=1: Y[k*T + tok]  (k-major, so argmax reads are lane-coalesced)
// ---------------------------------------------------------------------------
__global__ __launch_bounds__(256) void proj_head0_f64(
    const float* __restrict__ X, const float* __restrict__ W,
    const int* __restrict__ bseq, double* __restrict__ Y, const int T,
    const int transposed) {
  const int wave = (int)threadIdx.x >> 6, lane = (int)threadIdx.x & 63;
  const int tok = blockIdx.x * 4 + wave;
  if (tok >= T) return;
  const int B = clampi(bseq[tok], 0, NBUCK - 1);
  const float* xr = X + (size_t)tok * DMODEL;
  const float* wb = W + (size_t)B * DMODEL * (NHEAD * DK) + lane;  // W[B][d][lane]
  double acc = 0.0;
  #pragma unroll 4
  for (int d = 0; d < DMODEL; ++d)
    acc += (double)xr[d] * (double)wb[(size_t)d * (NHEAD * DK)];
  if (transposed) Y[(size_t)lane * T + tok] = acc;
  else            Y[(size_t)tok * 64 + lane] = acc;
}

// ---------------------------------------------------------------------------
// fp64 sidecar B: per q-row fp64 scores over all 1088 keys; exact
// first-occurrence argmax over [0,1024) -> sIdx and [1024,1088) -> aIdx.
// K0 is TRANSPOSED [64][T_INT]: inner k loop reads lanes-consecutive m ->
// fully coalesced loads.
// ---------------------------------------------------------------------------
__global__ __launch_bounds__(256) void argmax_f64(
    const double* __restrict__ Q0, const double* __restrict__ K0T,
    float* __restrict__ out_s, float* __restrict__ out_a) {
  const int n = blockIdx.x;          // b*1024 + nn
  const int b = n >> 10;
  const int t = (int)threadIdx.x;
  __shared__ double qs[64];
  __shared__ double bval[256];  __shared__ int bidx[256];
  __shared__ double bval2[256]; __shared__ int bidx2[256];
  if (t < 64) qs[t] = Q0[(size_t)n * 64 + t];
  __syncthreads();
  double v1 = -1e300; int i1 = 0x7FFFFFFF;
  double v2 = -1e300; int i2 = 0x7FFFFFFF;
  for (int m = t; m < NN2; m += 256) {
    const double* base = K0T + (size_t)b * NN2 + m;   // column m of K0T
    double s = 0.0;
    #pragma unroll 8
    for (int k = 0; k < 64; ++k) s += qs[k] * base[(size_t)k * T_INT];
    if (m < 1024) { if (s > v1 || (s == v1 && m < i1)) { v1 = s; i1 = m; } }
    else          { if (s > v2 || (s == v2 && m < i2)) { v2 = s; i2 = m; } }
  }
  bval[t] = v1; bidx[t] = i1; bval2[t] = v2; bidx2[t] = i2;
  __syncthreads();
  for (int off = 128; off >= 1; off >>= 1) {
    if (t < off) {
      if (bval[t+off] >  bval[t] || (bval[t+off] ==  bval[t] &&  bidx[t+off] <  bidx[t])) { bval[t]  = bval[t+off];  bidx[t]  = bidx[t+off]; }
      if (bval2[t+off] > bval2[t] || (bval2[t+off] == bval2[t] && bidx2[t+off] < bidx2[t])) { bval2[t] = bval2[t+off]; bidx2[t] = bidx2[t+off]; }
    }
    __syncthreads();
  }
  if (t == 0) {
    out_s[n] = (float)bidx[0];
    out_a[n] = (float)(bidx2[0] - 1024);
  }
}

// ---------------------------------------------------------------------------
// Kernel 2: FUSED grouped GEMM for q,k,v in one launch.  (R2 version, proven)
// blockIdx.z = g*9 + bucket, g=0:q(item,W_item) 1:k(intent,W_int[0]) 2:v(W_int[1])
// tile 128x128, BK=16, 512 threads (8 waves, 2/SIMD), 8x4 micro-tile.
// ---------------------------------------------------------------------------
#define TM  128
#define TN  128
#define GBK 16

__global__ __launch_bounds__(512) void gemm_grouped_fused(
    const float* __restrict__ item, const float* __restrict__ intent,
    const float* __restrict__ Wq, const float* __restrict__ Wk,
    const float* __restrict__ Wv,
    const int* __restrict__ list_item, const int* __restrict__ list_int,
    const int* __restrict__ cnt,
    float* __restrict__ qb, float* __restrict__ kb, float* __restrict__ vb) {
  const int z = blockIdx.z;
  const int g = z / 9, B = z - g * 9;
  const float* X;  const float* W;  const int* list;  float* Y;  int n, Tmax;
  if (g == 0) { X = item;   W = Wq; list = list_item; Y = qb; n = min(cnt[B], T_ITEM);         Tmax = T_ITEM; }
  else if (g == 1) { X = intent; W = Wk; list = list_int;  Y = kb; n = min(cnt[NBUCK + B], T_INT); Tmax = T_INT; }
  else { X = intent; W = Wv; list = list_int;  Y = vb; n = min(cnt[NBUCK + B], T_INT); Tmax = T_INT; }

  const int row0 = blockIdx.y * TM;
  if (row0 >= n) return;                 // uniform across block
  const int rows = min(TM, n - row0);
  const int c0 = blockIdx.x * TN;
  const int t = (int)threadIdx.x;

  __shared__ float Xs[GBK][TM + 4];   // k-major (transposed on store)
  __shared__ float Ws[GBK][TN + 4];

  const int tokA = t >> 2;            // 0..127
  const int kqA  = (t & 3) * 4;       // 0,4,8,12
  const int liA  = clampi(list[row0 + min(tokA, rows - 1)], 0, Tmax - 1);
  const float* xrow = X + (size_t)liA * DMODEL;
  const int kW = t >> 5;              // 0..15
  const int cW = (t & 31) * 4;        // 0..124

  const int ty = t >> 5;              // row group (8 rows), 0..15
  const int tx = t & 31;              // col group (4 cols), 0..31

  float acc[8][4];
  #pragma unroll
  for (int i = 0; i < 8; ++i)
    #pragma unroll
    for (int j = 0; j < 4; ++j) acc[i][j] = 0.f;

  for (int k0 = 0; k0 < DMODEL; k0 += GBK) {
    float4 xa = *(const float4*)(xrow + k0 + kqA);
    const float* wp = W + ((size_t)B * DMODEL + k0 + kW) * (size_t)(NHEAD * DK) + c0 + cW;
    float4 wa = *(const float4*)wp;

    Xs[kqA + 0][tokA] = xa.x; Xs[kqA + 1][tokA] = xa.y;
    Xs[kqA + 2][tokA] = xa.z; Xs[kqA + 3][tokA] = xa.w;
    *(float4*)&Ws[kW][cW] = wa;
    __syncthreads();

    #pragma unroll
    for (int kk = 0; kk < GBK; ++kk) {
      float a[8], bv[4];
      *(float4*)&a[0]  = *(const float4*)&Xs[kk][ty * 8];
      *(float4*)&a[4]  = *(const float4*)&Xs[kk][ty * 8 + 4];
      *(float4*)&bv[0] = *(const float4*)&Ws[kk][tx * 4];
      #pragma unroll
      for (int i = 0; i < 8; ++i)
        #pragma unroll
        for (int j = 0; j < 4; ++j)
          acc[i][j] = fmaf(a[i], bv[j], acc[i][j]);
    }
    __syncthreads();
  }

  #pragma unroll
  for (int i = 0; i < 8; ++i) {
    const int r = ty * 8 + i;
    if (r < rows) {
      const int tok = clampi(list[row0 + r], 0, Tmax - 1);
      float* yr = Y + (size_t)tok * (size_t)(NHEAD * DK) + c0 + tx * 4;
      *(float4*)yr = make_float4(acc[i][0], acc[i][1], acc[i][2], acc[i][3]);
    }
  }
}

// ---------------------------------------------------------------------------
// Kernel 3: fused attention: scores -> softmax -> exact top-16 per segment ->
//           sparse p@V.  (index outputs come from the fp64 sidecar)
// Block = 256 thr (4 waves), 16 q-rows per block (4 per wave).
//
// LDS-pipe relief vs R2: TWO key-chunks staged per Ks pass (Ks[128][68]),
// so each set of 4 uniform q ds_read_b128 serves 32 FMAs instead of 16.
// Per-wave LDS b128 ops drop 1428 -> ~950. q broadcast stays on the LDS
// pipe (R3's global-q was VMEM-latency-bound: reverted). FMA order per
// score (k ascending) unchanged -> output bitwise identical to R2.
// ---------------------------------------------------------------------------
__device__ __forceinline__ unsigned ordf(float v) {
  unsigned s = __float_as_uint(v);
  return s ^ ((unsigned)((int)s >> 31) | 0x80000000u);
}
__device__ __forceinline__ float unordf(unsigned u) {
  unsigned s = (u & 0x80000000u) ? (u ^ 0x80000000u) : ~u;
  return __uint_as_float(s);
}
__device__ __forceinline__ unsigned long long shfl_xor_u64(unsigned long long w, int off) {
  unsigned lo = __shfl_xor((unsigned)w, off);
  unsigned hi = __shfl_xor((unsigned)(w >> 32), off);
  return ((unsigned long long)hi << 32) | lo;
}

__global__ __launch_bounds__(256) void attn_kernel(
    const float* __restrict__ Q, const float* __restrict__ K,
    const float* __restrict__ V, float* __restrict__ outx) {
  const int b = blockIdx.z, h = blockIdx.y;
  const int n0 = blockIdx.x * 16;
  const int t = (int)threadIdx.x;
  const int wave = t >> 6, lane = t & 63;

  __shared__ float Qs[16][64];
  __shared__ float Ks[128][68];       // 2 chunks; +4 pad: conflict-free b128
  __shared__ int   kept_m[16][32];
  __shared__ float kept_p[16][32];

  {
    const int r = t >> 4, k4 = (t & 15) * 4;
    *(float4*)&Qs[r][k4] =
        *(const float4*)(Q + (size_t)(b * SEQLEN + n0 + r) * (NHEAD * DK) + h * DK + k4);
  }
  __syncthreads();

  const int r0 = wave * 4;
  float sv[4][17];                    // static-indexed (unrolled loops only)

  // ---- chunks 0..15 in pairs: stage 128 key rows, score both chunks ----
  #pragma unroll
  for (int cp = 0; cp < 8; ++cp) {
    if (cp > 0) __syncthreads();
    #pragma unroll
    for (int j = 0; j < 8; ++j) {
      const int row = (t >> 4) + 16 * j;          // 0..127
      const int k4 = (t & 15) * 4;
      *(float4*)&Ks[row][k4] =
          *(const float4*)(K + (size_t)(b * NN2 + cp * 128 + row) * (NHEAD * DK) + h * DK + k4);
    }
    __syncthreads();

    float a0 = 0.f, a1 = 0.f, a2 = 0.f, a3 = 0.f;     // chunk 2cp
    float e0 = 0.f, e1 = 0.f, e2 = 0.f, e3 = 0.f;     // chunk 2cp+1
    #pragma unroll 4
    for (int k4 = 0; k4 < 64; k4 += 4) {
      const float4 kA = *(const float4*)&Ks[lane][k4];
      const float4 kB = *(const float4*)&Ks[64 + lane][k4];
      const float4 q0 = *(const float4*)&Qs[r0 + 0][k4];   // wave-uniform: LDS broadcast
      const float4 q1 = *(const float4*)&Qs[r0 + 1][k4];
      const float4 q2 = *(const float4*)&Qs[r0 + 2][k4];
      const float4 q3 = *(const float4*)&Qs[r0 + 3][k4];
      a0 = fmaf(q0.x, kA.x, a0); a0 = fmaf(q0.y, kA.y, a0);
      a0 = fmaf(q0.z, kA.z, a0); a0 = fmaf(q0.w, kA.w, a0);
      a1 = fmaf(q1.x, kA.x, a1); a1 = fmaf(q1.y, kA.y, a1);
      a1 = fmaf(q1.z, kA.z, a1); a1 = fmaf(q1.w, kA.w, a1);
      a2 = fmaf(q2.x, kA.x, a2); a2 = fmaf(q2.y, kA.y, a2);
      a2 = fmaf(q2.z, kA.z, a2); a2 = fmaf(q2.w, kA.w, a2);
      a3 = fmaf(q3.x, kA.x, a3); a3 = fmaf(q3.y, kA.y, a3);
      a3 = fmaf(q3.z, kA.z, a3); a3 = fmaf(q3.w, kA.w, a3);
      e0 = fmaf(q0.x, kB.x, e0); e0 = fmaf(q0.y, kB.y, e0);
      e0 = fmaf(q0.z, kB.z, e0); e0 = fmaf(q0.w, kB.w, e0);
      e1 = fmaf(q1.x, kB.x, e1); e1 = fmaf(q1.y, kB.y, e1);
      e1 = fmaf(q1.z, kB.z, e1); e1 = fmaf(q1.w, kB.w, e1);
      e2 = fmaf(q2.x, kB.x, e2); e2 = fmaf(q2.y, kB.y, e2);
      e2 = fmaf(q2.z, kB.z, e2); e2 = fmaf(q2.w, kB.w, e2);
      e3 = fmaf(q3.x, kB.x, e3); e3 = fmaf(q3.y, kB.y, e3);
      e3 = fmaf(q3.z, kB.z, e3); e3 = fmaf(q3.w, kB.w, e3);
    }
    sv[0][2*cp] = a0 * 0.125f; sv[1][2*cp] = a1 * 0.125f;
    sv[2][2*cp] = a2 * 0.125f; sv[3][2*cp] = a3 * 0.125f;
    sv[0][2*cp+1] = e0 * 0.125f; sv[1][2*cp+1] = e1 * 0.125f;
    sv[2][2*cp+1] = e2 * 0.125f; sv[3][2*cp+1] = e3 * 0.125f;
  }

  // ---- chunk 16 (the NI tail): single-chunk epilogue ----
  {
    __syncthreads();
    #pragma unroll
    for (int j = 0; j < 4; ++j) {
      const int row = (t >> 4) + 16 * j;          // 0..63
      const int k4 = (t & 15) * 4;
      *(float4*)&Ks[row][k4] =
          *(const float4*)(K + (size_t)(b * NN2 + 1024 + row) * (NHEAD * DK) + h * DK + k4);
    }
    __syncthreads();

    float a0 = 0.f, a1 = 0.f, a2 = 0.f, a3 = 0.f;
    #pragma unroll 4
    for (int k4 = 0; k4 < 64; k4 += 4) {
      const float4 kA = *(const float4*)&Ks[lane][k4];
      const float4 q0 = *(const float4*)&Qs[r0 + 0][k4];
      const float4 q1 = *(const float4*)&Qs[r0 + 1][k4];
      const float4 q2 = *(const float4*)&Qs[r0 + 2][k4];
      const float4 q3 = *(const float4*)&Qs[r0 + 3][k4];
      a0 = fmaf(q0.x, kA.x, a0); a0 = fmaf(q0.y, kA.y, a0);
      a0 = fmaf(q0.z, kA.z, a0); a0 = fmaf(q0.w, kA.w, a0);
      a1 = fmaf(q1.x, kA.x, a1); a1 = fmaf(q1.y, kA.y, a1);
      a1 = fmaf(q1.z, kA.z, a1); a1 = fmaf(q1.w, kA.w, a1);
      a2 = fmaf(q2.x, kA.x, a2); a2 = fmaf(q2.y, kA.y, a2);
      a2 = fmaf(q2.z, kA.z, a2); a2 = fmaf(q2.w, kA.w, a2);
      a3 = fmaf(q3.x, kA.x, a3); a3 = fmaf(q3.y, kA.y, a3);
      a3 = fmaf(q3.z, kA.z, a3); a3 = fmaf(q3.w, kA.w, a3);
    }
    sv[0][16] = a0 * 0.125f; sv[1][16] = a1 * 0.125f;
    sv[2][16] = a2 * 0.125f; sv[3][16] = a3 * 0.125f;
  }

  // ---- softmax stats, 4 rows interleaved ----
  float M_[4], invL_[4];
  {
    float L_[4];
    #pragma unroll
    for (int r = 0; r < 4; ++r) {
      float M = -3.402823466e38f;
      #pragma unroll
      for (int c = 0; c < 17; ++c) M = fmaxf(M, sv[r][c]);
      M_[r] = M;
    }
    #pragma unroll
    for (int off = 32; off >= 1; off >>= 1) {
      #pragma unroll
      for (int r = 0; r < 4; ++r) M_[r] = fmaxf(M_[r], __shfl_xor(M_[r], off));
    }
    #pragma unroll
    for (int r = 0; r < 4; ++r) {
      float L = 0.f;
      #pragma unroll
      for (int c = 0; c < 17; ++c) L += __expf(sv[r][c] - M_[r]);
      L_[r] = L;
    }
    #pragma unroll
    for (int off = 32; off >= 1; off >>= 1) {
      #pragma unroll
      for (int r = 0; r < 4; ++r) L_[r] += __shfl_xor(L_[r], off);
    }
    #pragma unroll
    for (int r = 0; r < 4; ++r) invL_[r] = 1.0f / L_[r];
  }

  // ---- segment 1 keys + per-lane top-2 init ----
  unsigned kh[4][16];
  #pragma unroll
  for (int r = 0; r < 4; ++r)
    #pragma unroll
    for (int c = 0; c < 16; ++c) kh[r][c] = ordf(sv[r][c]);

  unsigned long long b1_[4], b2_[4];
  unsigned alive_[4];
  #pragma unroll
  for (int r = 0; r < 4; ++r) {
    unsigned long long b1 = 0ull, b2 = 0ull;
    #pragma unroll
    for (int c = 0; c < 16; ++c) {
      const unsigned long long k64 =
          ((unsigned long long)kh[r][c] << 32) | (unsigned)~(unsigned)(c * 64 + lane);
      const unsigned long long mn = (k64 < b1) ? k64 : b1;  // min(b1,k)
      b1 = (k64 > b1) ? k64 : b1;
      b2 = (mn > b2) ? mn : b2;
    }
    b1_[r] = b1; b2_[r] = b2; alive_[r] = 0xFFFFu;
  }

  // ---- segment 1: 16 extraction rounds, 4 rows interleaved ----
  for (int round = 0; round < TOPK; ++round) {
    unsigned long long w0 = b1_[0], w1 = b1_[1], w2 = b1_[2], w3 = b1_[3];
    #pragma unroll
    for (int off = 1; off < 64; off <<= 1) {
      unsigned long long o;
      o = shfl_xor_u64(w0, off); w0 = (o > w0) ? o : w0;
      o = shfl_xor_u64(w1, off); w1 = (o > w1) ? o : w1;
      o = shfl_xor_u64(w2, off); w2 = (o > w2) ? o : w2;
      o = shfl_xor_u64(w3, off); w3 = (o > w3) ? o : w3;
    }
    const unsigned long long ws[4] = {w0, w1, w2, w3};
    #pragma unroll
    for (int r = 0; r < 4; ++r) {
      const unsigned long long w = ws[r];
      const int m = (int)((~(unsigned)w) & 1023u);
      if (lane == round) {
        kept_m[r0 + r][round] = m;
        kept_p[r0 + r][round] = __expf(unordf((unsigned)(w >> 32)) - M_[r]) * invL_[r];
      }
      if ((m & 63) == lane) {          // winner lane bookkeeping
        alive_[r] &= ~(1u << (m >> 6));
        if (b2_[r]) { b1_[r] = b2_[r]; b2_[r] = 0ull; }
        else {
          unsigned long long mx = 0ull;
          #pragma unroll
          for (int c = 0; c < 16; ++c) {
            const unsigned long long k64 =
                ((unsigned long long)kh[r][c] << 32) | (unsigned)~(unsigned)(c * 64 + lane);
            if ((alive_[r] >> c) & 1u) mx = (k64 > mx) ? k64 : mx;
          }
          b1_[r] = mx;
        }
      }
    }
  }

  // ---- segment 2: bitonic sort (descending) of the 64 tail candidates ----
  {
    unsigned long long w_[4];
    #pragma unroll
    for (int r = 0; r < 4; ++r)
      w_[r] = ((unsigned long long)ordf(sv[r][16]) << 32) | (unsigned)~(unsigned)lane;
    #pragma unroll
    for (int k = 2; k <= 64; k <<= 1) {
      #pragma unroll
      for (int j = k >> 1; j >= 1; j >>= 1) {
        const bool tm = (((lane & j) != 0) == ((lane & k) != 0));
        #pragma unroll
        for (int r = 0; r < 4; ++r) {
          const unsigned long long o = shfl_xor_u64(w_[r], j);
          w_[r] = ((o > w_[r]) == tm) ? o : w_[r];
        }
      }
    }
    if (lane < TOPK) {
      #pragma unroll
      for (int r = 0; r < 4; ++r) {
        kept_m[r0 + r][TOPK + lane] = 1024 + (int)((~(unsigned)w_[r]) & 63u);
        kept_p[r0 + r][TOPK + lane] =
            __expf(unordf((unsigned)(w_[r] >> 32)) - M_[r]) * invL_[r];
      }
    }
  }
  __syncthreads();

  #pragma unroll
  for (int rr = 0; rr < 4; ++rr) {
    const int r_loc = wave * 4 + rr;
    const int n = n0 + r_loc;
    float x = 0.f;
    #pragma unroll
    for (int i = 0; i < 32; ++i) {
      const int m = clampi(kept_m[r_loc][i], 0, NN2 - 1);
      const float p = kept_p[r_loc][i];
      x = fmaf(p, V[(size_t)(b * NN2 + m) * (NHEAD * DK) + h * DK + lane], x);
    }
    outx[(size_t)(b * SEQLEN + n) * (NHEAD * DK) + h * DK + lane] = x;
  }
}

// ---------------------------------------------------------------------------
extern "C" void kernel_launch(void* const* d_in, const int* in_sizes, int n_in,
                              void* d_out, int out_size, void* d_ws, size_t ws_size,
                              hipStream_t stream) {
  const float* item    = (const float*)d_in[0];
  const float* intent  = (const float*)d_in[1];
  // d_in[2] = mask: constant all-True -> no-op, skipped
  const int*   b_seq   = (const int*)d_in[3];
  const int*   b_seq2  = (const int*)d_in[4];
  const float* W_item  = (const float*)d_in[5];   // [9][1024][16][64]
  const float* W_int   = (const float*)d_in[6];   // [2][9][1024][16][64]

  if (ws_size < WS_NEED) return;   // clean failure instead of device fault

  char* ws = (char*)d_ws;
  float* qb = (float*)(ws + Q_OFF);
  float* kb = (float*)(ws + K_OFF);
  float* vb = (float*)(ws + V_OFF);
  double* q0d = (double*)(ws + Q0D_OFF);   // aliases V region (used before v-GEMM)
  double* k0dT = (double*)(ws + K0D_OFF);  // transposed [64][T_INT]
  int* cnt       = (int*)(ws + CNT_OFF);
  int* list_item = (int*)(ws + LI_OFF);
  int* list_int  = (int*)(ws + LN_OFF);

  float* outx  = (float*)d_out;
  float* out_s = outx + X_OUT_ELEMS;
  float* out_a = out_s + SIDX_ELEMS;

  hipMemsetAsync(cnt, 0, 128, stream);
  bucketize_kernel<<<dim3(9), 256, 0, stream>>>(b_seq, b_seq2, cnt, list_item, list_int);

  // fp64 sidecar: head-0 q/k projections + exact argmax -> sIdx, aIdx.
  proj_head0_f64<<<dim3((T_ITEM + 3) / 4), 256, 0, stream>>>(item, W_item, b_seq, q0d, T_ITEM, 0);
  proj_head0_f64<<<dim3((T_INT + 3) / 4), 256, 0, stream>>>(intent, W_int, b_seq2, k0dT, T_INT, 1);
  argmax_f64<<<dim3(T_ITEM), 256, 0, stream>>>(q0d, k0dT, out_s, out_a);

  // fused fp32 q/k/v grouped GEMM (runs after argmax; v-write aliases sidecar)
  gemm_grouped_fused<<<dim3(8, 17, 27), 512, 0, stream>>>(
      item, intent,
      W_item, W_int, W_int + (size_t)NBUCK * DMODEL * (NHEAD * DK),
      list_item, list_int, cnt, qb, kb, vb);

  attn_kernel<<<dim3(SEQLEN / 16, NHEAD, BSZ), 256, 0, stream>>>(qb, kb, vb, outx);
}

// Round 5
// 748.211 us; speedup vs baseline: 1.5483x; 1.2547x over previous
//
#include <hip/hip_runtime.h>

// Problem constants (match reference)
#define NHEAD   16
#define DK      64
#define DMODEL  1024
#define BSZ     2
#define SEQLEN  1024
#define NI      64
#define NN2     1088          // SEQLEN + NI
#define NBUCK   9             // N_B + 1
#define TOPK    16

#define T_ITEM  (BSZ*SEQLEN)  // 2048 item tokens
#define T_INT   (BSZ*NN2)     // 2176 intent tokens

// workspace layout (bytes). total ~26.4 MB
#define Q_OFF   ((size_t)0)                          // q: 2048x1024 f32
#define K_OFF   (Q_OFF + (size_t)T_ITEM*DMODEL*4)    // k: 2176x1024 f32
#define V_OFF   (K_OFF + (size_t)T_INT*DMODEL*4)     // v: 2176x1024 f32
#define CNT_OFF (V_OFF + (size_t)T_INT*DMODEL*4)     // counts: 18 ints
#define LI_OFF  (CNT_OFF + 128)                      // item lists 9x2048
#define LN_OFF  (LI_OFF + (size_t)NBUCK*T_ITEM*4)    // intent lists 9x2176
#define WS_NEED (LN_OFF + (size_t)NBUCK*T_INT*4)

// fp64 sidecar buffers live INSIDE the V region (used before v-GEMM writes it):
//   q0d: 2048*64 f64 row-major (1 MB), k0dT: 64 x 2176 f64 TRANSPOSED (1.1 MB)
#define Q0D_OFF V_OFF
#define K0D_OFF (V_OFF + (size_t)T_ITEM*64*8)

#define X_OUT_ELEMS ((size_t)BSZ*SEQLEN*DMODEL)      // 2,097,152
#define SIDX_ELEMS  ((size_t)BSZ*SEQLEN)             // 2048

__device__ __forceinline__ int clampi(int v, int lo, int hi) {
  return v < lo ? lo : (v > hi ? hi : v);
}

// ---------------------------------------------------------------------------
// Kernel 1: counting-sort tokens into buckets (order within bucket irrelevant)
// ---------------------------------------------------------------------------
__global__ void bucketize_kernel(const int* __restrict__ b_seq, const int* __restrict__ b_seq2,
                                 int* __restrict__ cnt, int* __restrict__ list_item,
                                 int* __restrict__ list_int) {
  int t = blockIdx.x * blockDim.x + threadIdx.x;
  if (t < T_ITEM) {
    int B = clampi(b_seq[t], 0, NBUCK - 1);
    int p = atomicAdd(&cnt[B], 1);
    if (p >= 0 && p < T_ITEM) list_item[B * T_ITEM + p] = t;
  }
  if (t < T_INT) {
    int B = clampi(b_seq2[t], 0, NBUCK - 1);
    int p = atomicAdd(&cnt[NBUCK + B], 1);
    if (p >= 0 && p < T_INT) list_int[B * T_INT + p] = t;
  }
}

// ---------------------------------------------------------------------------
// fp64 sidecar A (v2): head-0 projection for BOTH item and intent in one
// launch. One block (256 thr = 4 waves) per token; each wave accumulates a
// 256-long d-slice (serial chain 1024 -> 256), partials reduced in LDS in
// fixed order w0+w1+w2+w3 (f64, ~1e-15 rel error -> argmax ordering safe).
// blk <  T_ITEM: item -> q0d row-major.  blk >= T_ITEM: intent -> k0dT
// transposed [64][T_INT] so argmax reads are lane-coalesced.
// ---------------------------------------------------------------------------
__global__ __launch_bounds__(256) void proj_head0_f64_v2(
    const float* __restrict__ item, const float* __restrict__ intent,
    const float* __restrict__ Wq, const float* __restrict__ Wk,
    const int* __restrict__ b_seq, const int* __restrict__ b_seq2,
    double* __restrict__ q0d, double* __restrict__ k0dT) {
  const int blk = blockIdx.x;
  const int wv = (int)threadIdx.x >> 6, lane = (int)threadIdx.x & 63;
  const float* X; const float* W; const int* bs; int tok; bool tr;
  if (blk < T_ITEM) { tok = blk;          X = item;   W = Wq; bs = b_seq;  tr = false; }
  else              { tok = blk - T_ITEM; X = intent; W = Wk; bs = b_seq2; tr = true; }
  const int B = clampi(bs[tok], 0, NBUCK - 1);
  const float* xr = X + (size_t)tok * DMODEL;
  const float* wb = W + (size_t)B * DMODEL * (NHEAD * DK) + lane;  // W[B][d][lane]
  double acc = 0.0;
  const int d0 = wv * 256;
  #pragma unroll 8
  for (int d = d0; d < d0 + 256; ++d)
    acc += (double)xr[d] * (double)wb[(size_t)d * (NHEAD * DK)];
  __shared__ double part[4][64];
  part[wv][lane] = acc;
  __syncthreads();
  if (wv == 0) {
    double s = ((part[0][lane] + part[1][lane]) + part[2][lane]) + part[3][lane];
    if (tr) k0dT[(size_t)lane * T_INT + tok] = s;
    else    q0d[(size_t)tok * 64 + lane] = s;
  }
}

// ---------------------------------------------------------------------------
// fp64 sidecar B (v2): 4 q-rows per block. Each K0T column load feeds 4
// independent f64 dot chains (traffic /4, ILP x4). Per-row dot order
// (k ascending) and tie-break identical to v1 -> bitwise-same indices.
// 2048/4 = 512 blocks; 4-row groups never straddle the batch boundary
// (1024 % 4 == 0).
// ---------------------------------------------------------------------------
#define AR 4
__global__ __launch_bounds__(256) void argmax_f64_v2(
    const double* __restrict__ Q0, const double* __restrict__ K0T,
    float* __restrict__ out_s, float* __restrict__ out_a) {
  const int n0 = blockIdx.x * AR;    // q-row base; b uniform within block
  const int b = n0 >> 10;
  const int t = (int)threadIdx.x;
  __shared__ double qs[AR][64];
  qs[t >> 6][t & 63] = Q0[(size_t)(n0 + (t >> 6)) * 64 + (t & 63)];
  __syncthreads();
  double v1[AR], v2[AR]; int i1[AR], i2[AR];
  #pragma unroll
  for (int r = 0; r < AR; ++r) {
    v1[r] = -1e300; i1[r] = 0x7FFFFFFF;
    v2[r] = -1e300; i2[r] = 0x7FFFFFFF;
  }
  for (int m = t; m < NN2; m += 256) {
    const double* base = K0T + (size_t)b * NN2 + m;   // column m of K0T
    double s0 = 0.0, s1 = 0.0, s2 = 0.0, s3 = 0.0;
    #pragma unroll 8
    for (int k = 0; k < 64; ++k) {
      const double kv = base[(size_t)k * T_INT];
      s0 += qs[0][k] * kv; s1 += qs[1][k] * kv;
      s2 += qs[2][k] * kv; s3 += qs[3][k] * kv;
    }
    const double ss[AR] = {s0, s1, s2, s3};
    #pragma unroll
    for (int r = 0; r < AR; ++r) {
      const double s = ss[r];
      if (m < 1024) { if (s > v1[r] || (s == v1[r] && m < i1[r])) { v1[r] = s; i1[r] = m; } }
      else          { if (s > v2[r] || (s == v2[r] && m < i2[r])) { v2[r] = s; i2[r] = m; } }
    }
  }
  __shared__ double bval[256];  __shared__ int bidx[256];
  __shared__ double bval2[256]; __shared__ int bidx2[256];
  for (int r = 0; r < AR; ++r) {
    __syncthreads();
    bval[t] = v1[r]; bidx[t] = i1[r]; bval2[t] = v2[r]; bidx2[t] = i2[r];
    __syncthreads();
    for (int off = 128; off >= 1; off >>= 1) {
      if (t < off) {
        if (bval[t+off] >  bval[t] || (bval[t+off] ==  bval[t] &&  bidx[t+off] <  bidx[t])) { bval[t]  = bval[t+off];  bidx[t]  = bidx[t+off]; }
        if (bval2[t+off] > bval2[t] || (bval2[t+off] == bval2[t] && bidx2[t+off] < bidx2[t])) { bval2[t] = bval2[t+off]; bidx2[t] = bidx2[t+off]; }
      }
      __syncthreads();
    }
    if (t == 0) {
      out_s[n0 + r] = (float)bidx[0];
      out_a[n0 + r] = (float)(bidx2[0] - 1024);
    }
  }
}

// ---------------------------------------------------------------------------
// Kernel 2: FUSED grouped GEMM (v2): tile 128x64, 256 threads (4 waves),
// 8x4 micro-tile, register double-buffer prefetch.
//  * TN 128->64 doubles the grid (864 active blocks -> ~3.4 blocks/CU; R4
//    measured 27% occupancy = ~1 block/CU so barriers exposed all latency).
//  * next K-step's global loads issued BEFORE compute, stored after the
//    barrier -> staging latency hidden under the 512-FMA compute phase.
// Per-output FMA order (k0 asc, kk asc) unchanged -> bitwise-identical Y.
// ---------------------------------------------------------------------------
#define GTM 128
#define GTN 64
#define GBK 16

__global__ __launch_bounds__(256) void gemm_grouped_fused(
    const float* __restrict__ item, const float* __restrict__ intent,
    const float* __restrict__ Wq, const float* __restrict__ Wk,
    const float* __restrict__ Wv,
    const int* __restrict__ list_item, const int* __restrict__ list_int,
    const int* __restrict__ cnt,
    float* __restrict__ qb, float* __restrict__ kb, float* __restrict__ vb) {
  const int z = blockIdx.z;
  const int g = z / 9, B = z - g * 9;
  const float* X;  const float* W;  const int* list;  float* Y;  int n, Tmax;
  if (g == 0)      { X = item;   W = Wq; list = list_item; Y = qb; n = min(cnt[B], T_ITEM);         Tmax = T_ITEM; }
  else if (g == 1) { X = intent; W = Wk; list = list_int;  Y = kb; n = min(cnt[NBUCK + B], T_INT); Tmax = T_INT; }
  else             { X = intent; W = Wv; list = list_int;  Y = vb; n = min(cnt[NBUCK + B], T_INT); Tmax = T_INT; }

  const int row0 = blockIdx.y * GTM;
  if (row0 >= n) return;                 // uniform across block
  const int rows = min(GTM, n - row0);
  const int c0 = blockIdx.x * GTN;
  const int t = (int)threadIdx.x;

  __shared__ float Xs[GBK][GTM + 4];   // k-major (transposed on store)
  __shared__ float Ws[GBK][GTN + 4];

  const int tokA = t >> 1;            // 0..127
  const int kqA  = (t & 1) * 8;       // 0 or 8
  const int liA  = clampi(list[row0 + min(tokA, rows - 1)], 0, Tmax - 1);
  const float* xrow = X + (size_t)liA * DMODEL;
  const int kW = t >> 4;              // 0..15
  const int cW = (t & 15) * 4;        // 0..60
  const float* wbase = W + ((size_t)B * DMODEL + kW) * (size_t)(NHEAD * DK) + c0 + cW;

  const int ty = t >> 4;              // 0..15 -> rows ty*8..+7
  const int tx = t & 15;              // 0..15 -> cols tx*4..+3

  float acc[8][4];
  #pragma unroll
  for (int i = 0; i < 8; ++i)
    #pragma unroll
    for (int j = 0; j < 4; ++j) acc[i][j] = 0.f;

  // prefetch k0 = 0
  float4 xa = *(const float4*)(xrow + kqA);
  float4 xb = *(const float4*)(xrow + kqA + 4);
  float4 wa = *(const float4*)wbase;

  for (int k0 = 0; k0 < DMODEL; k0 += GBK) {
    __syncthreads();                       // previous tile fully consumed
    Xs[kqA + 0][tokA] = xa.x; Xs[kqA + 1][tokA] = xa.y;
    Xs[kqA + 2][tokA] = xa.z; Xs[kqA + 3][tokA] = xa.w;
    Xs[kqA + 4][tokA] = xb.x; Xs[kqA + 5][tokA] = xb.y;
    Xs[kqA + 6][tokA] = xb.z; Xs[kqA + 7][tokA] = xb.w;
    *(float4*)&Ws[kW][cW] = wa;
    __syncthreads();

    if (k0 + GBK < DMODEL) {               // issue next tile's loads now;
      xa = *(const float4*)(xrow + k0 + GBK + kqA);          // waited at the
      xb = *(const float4*)(xrow + k0 + GBK + kqA + 4);      // NEXT store ->
      wa = *(const float4*)(wbase + (size_t)(k0 + GBK) * (NHEAD * DK)); // hidden
    }

    #pragma unroll
    for (int kk = 0; kk < GBK; ++kk) {
      float a[8], bv[4];
      *(float4*)&a[0]  = *(const float4*)&Xs[kk][ty * 8];
      *(float4*)&a[4]  = *(const float4*)&Xs[kk][ty * 8 + 4];
      *(float4*)&bv[0] = *(const float4*)&Ws[kk][tx * 4];
      #pragma unroll
      for (int i = 0; i < 8; ++i)
        #pragma unroll
        for (int j = 0; j < 4; ++j)
          acc[i][j] = fmaf(a[i], bv[j], acc[i][j]);
    }
  }

  #pragma unroll
  for (int i = 0; i < 8; ++i) {
    const int r = ty * 8 + i;
    if (r < rows) {
      const int tok = clampi(list[row0 + r], 0, Tmax - 1);
      float* yr = Y + (size_t)tok * (size_t)(NHEAD * DK) + c0 + tx * 4;
      *(float4*)yr = make_float4(acc[i][0], acc[i][1], acc[i][2], acc[i][3]);
    }
  }
}

// ---------------------------------------------------------------------------
// Kernel 3: fused attention (unchanged from R4: double-chunk Ks staging).
// ---------------------------------------------------------------------------
__device__ __forceinline__ unsigned ordf(float v) {
  unsigned s = __float_as_uint(v);
  return s ^ ((unsigned)((int)s >> 31) | 0x80000000u);
}
__device__ __forceinline__ float unordf(unsigned u) {
  unsigned s = (u & 0x80000000u) ? (u ^ 0x80000000u) : ~u;
  return __uint_as_float(s);
}
__device__ __forceinline__ unsigned long long shfl_xor_u64(unsigned long long w, int off) {
  unsigned lo = __shfl_xor((unsigned)w, off);
  unsigned hi = __shfl_xor((unsigned)(w >> 32), off);
  return ((unsigned long long)hi << 32) | lo;
}

__global__ __launch_bounds__(256) void attn_kernel(
    const float* __restrict__ Q, const float* __restrict__ K,
    const float* __restrict__ V, float* __restrict__ outx) {
  const int b = blockIdx.z, h = blockIdx.y;
  const int n0 = blockIdx.x * 16;
  const int t = (int)threadIdx.x;
  const int wave = t >> 6, lane = t & 63;

  __shared__ float Qs[16][64];
  __shared__ float Ks[128][68];       // 2 chunks; +4 pad: conflict-free b128
  __shared__ int   kept_m[16][32];
  __shared__ float kept_p[16][32];

  {
    const int r = t >> 4, k4 = (t & 15) * 4;
    *(float4*)&Qs[r][k4] =
        *(const float4*)(Q + (size_t)(b * SEQLEN + n0 + r) * (NHEAD * DK) + h * DK + k4);
  }
  __syncthreads();

  const int r0 = wave * 4;
  float sv[4][17];                    // static-indexed (unrolled loops only)

  // ---- chunks 0..15 in pairs: stage 128 key rows, score both chunks ----
  #pragma unroll
  for (int cp = 0; cp < 8; ++cp) {
    if (cp > 0) __syncthreads();
    #pragma unroll
    for (int j = 0; j < 8; ++j) {
      const int row = (t >> 4) + 16 * j;          // 0..127
      const int k4 = (t & 15) * 4;
      *(float4*)&Ks[row][k4] =
          *(const float4*)(K + (size_t)(b * NN2 + cp * 128 + row) * (NHEAD * DK) + h * DK + k4);
    }
    __syncthreads();

    float a0 = 0.f, a1 = 0.f, a2 = 0.f, a3 = 0.f;     // chunk 2cp
    float e0 = 0.f, e1 = 0.f, e2 = 0.f, e3 = 0.f;     // chunk 2cp+1
    #pragma unroll 4
    for (int k4 = 0; k4 < 64; k4 += 4) {
      const float4 kA = *(const float4*)&Ks[lane][k4];
      const float4 kB = *(const float4*)&Ks[64 + lane][k4];
      const float4 q0 = *(const float4*)&Qs[r0 + 0][k4];   // wave-uniform: LDS broadcast
      const float4 q1 = *(const float4*)&Qs[r0 + 1][k4];
      const float4 q2 = *(const float4*)&Qs[r0 + 2][k4];
      const float4 q3 = *(const float4*)&Qs[r0 + 3][k4];
      a0 = fmaf(q0.x, kA.x, a0); a0 = fmaf(q0.y, kA.y, a0);
      a0 = fmaf(q0.z, kA.z, a0); a0 = fmaf(q0.w, kA.w, a0);
      a1 = fmaf(q1.x, kA.x, a1); a1 = fmaf(q1.y, kA.y, a1);
      a1 = fmaf(q1.z, kA.z, a1); a1 = fmaf(q1.w, kA.w, a1);
      a2 = fmaf(q2.x, kA.x, a2); a2 = fmaf(q2.y, kA.y, a2);
      a2 = fmaf(q2.z, kA.z, a2); a2 = fmaf(q2.w, kA.w, a2);
      a3 = fmaf(q3.x, kA.x, a3); a3 = fmaf(q3.y, kA.y, a3);
      a3 = fmaf(q3.z, kA.z, a3); a3 = fmaf(q3.w, kA.w, a3);
      e0 = fmaf(q0.x, kB.x, e0); e0 = fmaf(q0.y, kB.y, e0);
      e0 = fmaf(q0.z, kB.z, e0); e0 = fmaf(q0.w, kB.w, e0);
      e1 = fmaf(q1.x, kB.x, e1); e1 = fmaf(q1.y, kB.y, e1);
      e1 = fmaf(q1.z, kB.z, e1); e1 = fmaf(q1.w, kB.w, e1);
      e2 = fmaf(q2.x, kB.x, e2); e2 = fmaf(q2.y, kB.y, e2);
      e2 = fmaf(q2.z, kB.z, e2); e2 = fmaf(q2.w, kB.w, e2);
      e3 = fmaf(q3.x, kB.x, e3); e3 = fmaf(q3.y, kB.y, e3);
      e3 = fmaf(q3.z, kB.z, e3); e3 = fmaf(q3.w, kB.w, e3);
    }
    sv[0][2*cp] = a0 * 0.125f; sv[1][2*cp] = a1 * 0.125f;
    sv[2][2*cp] = a2 * 0.125f; sv[3][2*cp] = a3 * 0.125f;
    sv[0][2*cp+1] = e0 * 0.125f; sv[1][2*cp+1] = e1 * 0.125f;
    sv[2][2*cp+1] = e2 * 0.125f; sv[3][2*cp+1] = e3 * 0.125f;
  }

  // ---- chunk 16 (the NI tail): single-chunk epilogue ----
  {
    __syncthreads();
    #pragma unroll
    for (int j = 0; j < 4; ++j) {
      const int row = (t >> 4) + 16 * j;          // 0..63
      const int k4 = (t & 15) * 4;
      *(float4*)&Ks[row][k4] =
          *(const float4*)(K + (size_t)(b * NN2 + 1024 + row) * (NHEAD * DK) + h * DK + k4);
    }
    __syncthreads();

    float a0 = 0.f, a1 = 0.f, a2 = 0.f, a3 = 0.f;
    #pragma unroll 4
    for (int k4 = 0; k4 < 64; k4 += 4) {
      const float4 kA = *(const float4*)&Ks[lane][k4];
      const float4 q0 = *(const float4*)&Qs[r0 + 0][k4];
      const float4 q1 = *(const float4*)&Qs[r0 + 1][k4];
      const float4 q2 = *(const float4*)&Qs[r0 + 2][k4];
      const float4 q3 = *(const float4*)&Qs[r0 + 3][k4];
      a0 = fmaf(q0.x, kA.x, a0); a0 = fmaf(q0.y, kA.y, a0);
      a0 = fmaf(q0.z, kA.z, a0); a0 = fmaf(q0.w, kA.w, a0);
      a1 = fmaf(q1.x, kA.x, a1); a1 = fmaf(q1.y, kA.y, a1);
      a1 = fmaf(q1.z, kA.z, a1); a1 = fmaf(q1.w, kA.w, a1);
      a2 = fmaf(q2.x, kA.x, a2); a2 = fmaf(q2.y, kA.y, a2);
      a2 = fmaf(q2.z, kA.z, a2); a2 = fmaf(q2.w, kA.w, a2);
      a3 = fmaf(q3.x, kA.x, a3); a3 = fmaf(q3.y, kA.y, a3);
      a3 = fmaf(q3.z, kA.z, a3); a3 = fmaf(q3.w, kA.w, a3);
    }
    sv[0][16] = a0 * 0.125f; sv[1][16] = a1 * 0.125f;
    sv[2][16] = a2 * 0.125f; sv[3][16] = a3 * 0.125f;
  }

  // ---- softmax stats, 4 rows interleaved ----
  float M_[4], invL_[4];
  {
    float L_[4];
    #pragma unroll
    for (int r = 0; r < 4; ++r) {
      float M = -3.402823466e38f;
      #pragma unroll
      for (int c = 0; c < 17; ++c) M = fmaxf(M, sv[r][c]);
      M_[r] = M;
    }
    #pragma unroll
    for (int off = 32; off >= 1; off >>= 1) {
      #pragma unroll
      for (int r = 0; r < 4; ++r) M_[r] = fmaxf(M_[r], __shfl_xor(M_[r], off));
    }
    #pragma unroll
    for (int r = 0; r < 4; ++r) {
      float L = 0.f;
      #pragma unroll
      for (int c = 0; c < 17; ++c) L += __expf(sv[r][c] - M_[r]);
      L_[r] = L;
    }
    #pragma unroll
    for (int off = 32; off >= 1; off >>= 1) {
      #pragma unroll
      for (int r = 0; r < 4; ++r) L_[r] += __shfl_xor(L_[r], off);
    }
    #pragma unroll
    for (int r = 0; r < 4; ++r) invL_[r] = 1.0f / L_[r];
  }

  // ---- segment 1 keys + per-lane top-2 init ----
  unsigned kh[4][16];
  #pragma unroll
  for (int r = 0; r < 4; ++r)
    #pragma unroll
    for (int c = 0; c < 16; ++c) kh[r][c] = ordf(sv[r][c]);

  unsigned long long b1_[4], b2_[4];
  unsigned alive_[4];
  #pragma unroll
  for (int r = 0; r < 4; ++r) {
    unsigned long long b1 = 0ull, b2 = 0ull;
    #pragma unroll
    for (int c = 0; c < 16; ++c) {
      const unsigned long long k64 =
          ((unsigned long long)kh[r][c] << 32) | (unsigned)~(unsigned)(c * 64 + lane);
      const unsigned long long mn = (k64 < b1) ? k64 : b1;  // min(b1,k)
      b1 = (k64 > b1) ? k64 : b1;
      b2 = (mn > b2) ? mn : b2;
    }
    b1_[r] = b1; b2_[r] = b2; alive_[r] = 0xFFFFu;
  }

  // ---- segment 1: 16 extraction rounds, 4 rows interleaved ----
  for (int round = 0; round < TOPK; ++round) {
    unsigned long long w0 = b1_[0], w1 = b1_[1], w2 = b1_[2], w3 = b1_[3];
    #pragma unroll
    for (int off = 1; off < 64; off <<= 1) {
      unsigned long long o;
      o = shfl_xor_u64(w0, off); w0 = (o > w0) ? o : w0;
      o = shfl_xor_u64(w1, off); w1 = (o > w1) ? o : w1;
      o = shfl_xor_u64(w2, off); w2 = (o > w2) ? o : w2;
      o = shfl_xor_u64(w3, off); w3 = (o > w3) ? o : w3;
    }
    const unsigned long long ws[4] = {w0, w1, w2, w3};
    #pragma unroll
    for (int r = 0; r < 4; ++r) {
      const unsigned long long w = ws[r];
      const int m = (int)((~(unsigned)w) & 1023u);
      if (lane == round) {
        kept_m[r0 + r][round] = m;
        kept_p[r0 + r][round] = __expf(unordf((unsigned)(w >> 32)) - M_[r]) * invL_[r];
      }
      if ((m & 63) == lane) {          // winner lane bookkeeping
        alive_[r] &= ~(1u << (m >> 6));
        if (b2_[r]) { b1_[r] = b2_[r]; b2_[r] = 0ull; }
        else {
          unsigned long long mx = 0ull;
          #pragma unroll
          for (int c = 0; c < 16; ++c) {
            const unsigned long long k64 =
                ((unsigned long long)kh[r][c] << 32) | (unsigned)~(unsigned)(c * 64 + lane);
            if ((alive_[r] >> c) & 1u) mx = (k64 > mx) ? k64 : mx;
          }
          b1_[r] = mx;
        }
      }
    }
  }

  // ---- segment 2: bitonic sort (descending) of the 64 tail candidates ----
  {
    unsigned long long w_[4];
    #pragma unroll
    for (int r = 0; r < 4; ++r)
      w_[r] = ((unsigned long long)ordf(sv[r][16]) << 32) | (unsigned)~(unsigned)lane;
    #pragma unroll
    for (int k = 2; k <= 64; k <<= 1) {
      #pragma unroll
      for (int j = k >> 1; j >= 1; j >>= 1) {
        const bool tm = (((lane & j) != 0) == ((lane & k) != 0));
        #pragma unroll
        for (int r = 0; r < 4; ++r) {
          const unsigned long long o = shfl_xor_u64(w_[r], j);
          w_[r] = ((o > w_[r]) == tm) ? o : w_[r];
        }
      }
    }
    if (lane < TOPK) {
      #pragma unroll
      for (int r = 0; r < 4; ++r) {
        kept_m[r0 + r][TOPK + lane] = 1024 + (int)((~(unsigned)w_[r]) & 63u);
        kept_p[r0 + r][TOPK + lane] =
            __expf(unordf((unsigned)(w_[r] >> 32)) - M_[r]) * invL_[r];
      }
    }
  }
  __syncthreads();

  #pragma unroll
  for (int rr = 0; rr < 4; ++rr) {
    const int r_loc = wave * 4 + rr;
    const int n = n0 + r_loc;
    float x = 0.f;
    #pragma unroll
    for (int i = 0; i < 32; ++i) {
      const int m = clampi(kept_m[r_loc][i], 0, NN2 - 1);
      const float p = kept_p[r_loc][i];
      x = fmaf(p, V[(size_t)(b * NN2 + m) * (NHEAD * DK) + h * DK + lane], x);
    }
    outx[(size_t)(b * SEQLEN + n) * (NHEAD * DK) + h * DK + lane] = x;
  }
}

// ---------------------------------------------------------------------------
extern "C" void kernel_launch(void* const* d_in, const int* in_sizes, int n_in,
                              void* d_out, int out_size, void* d_ws, size_t ws_size,
                              hipStream_t stream) {
  const float* item    = (const float*)d_in[0];
  const float* intent  = (const float*)d_in[1];
  // d_in[2] = mask: constant all-True -> no-op, skipped
  const int*   b_seq   = (const int*)d_in[3];
  const int*   b_seq2  = (const int*)d_in[4];
  const float* W_item  = (const float*)d_in[5];   // [9][1024][16][64]
  const float* W_int   = (const float*)d_in[6];   // [2][9][1024][16][64]

  if (ws_size < WS_NEED) return;   // clean failure instead of device fault

  char* ws = (char*)d_ws;
  float* qb = (float*)(ws + Q_OFF);
  float* kb = (float*)(ws + K_OFF);
  float* vb = (float*)(ws + V_OFF);
  double* q0d = (double*)(ws + Q0D_OFF);   // aliases V region (used before v-GEMM)
  double* k0dT = (double*)(ws + K0D_OFF);  // transposed [64][T_INT]
  int* cnt       = (int*)(ws + CNT_OFF);
  int* list_item = (int*)(ws + LI_OFF);
  int* list_int  = (int*)(ws + LN_OFF);

  float* outx  = (float*)d_out;
  float* out_s = outx + X_OUT_ELEMS;
  float* out_a = out_s + SIDX_ELEMS;

  hipMemsetAsync(cnt, 0, 128, stream);
  bucketize_kernel<<<dim3(9), 256, 0, stream>>>(b_seq, b_seq2, cnt, list_item, list_int);

  // fp64 sidecar: fused head-0 q/k projections (one launch) + 4-row argmax.
  proj_head0_f64_v2<<<dim3(T_ITEM + T_INT), 256, 0, stream>>>(
      item, intent, W_item, W_int, b_seq, b_seq2, q0d, k0dT);
  argmax_f64_v2<<<dim3(T_ITEM / AR), 256, 0, stream>>>(q0d, k0dT, out_s, out_a);

  // fused fp32 q/k/v grouped GEMM (runs after argmax; v-write aliases sidecar)
  gemm_grouped_fused<<<dim3((NHEAD * DK) / GTN, 17, 27), 256, 0, stream>>>(
      item, intent,
      W_item, W_int, W_int + (size_t)NBUCK * DMODEL * (NHEAD * DK),
      list_item, list_int, cnt, qb, kb, vb);

  attn_kernel<<<dim3(SEQLEN / 16, NHEAD, BSZ), 256, 0, stream>>>(qb, kb, vb, outx);
}

// Round 6
// 709.218 us; speedup vs baseline: 1.6334x; 1.0550x over previous
//
#include <hip/hip_runtime.h>

// Problem constants (match reference)
#define NHEAD   16
#define DK      64
#define DMODEL  1024
#define BSZ     2
#define SEQLEN  1024
#define NI      64
#define NN2     1088          // SEQLEN + NI
#define NBUCK   9             // N_B + 1
#define TOPK    16

#define T_ITEM  (BSZ*SEQLEN)  // 2048 item tokens
#define T_INT   (BSZ*NN2)     // 2176 intent tokens

// workspace layout (bytes). total ~26.4 MB
#define Q_OFF   ((size_t)0)                          // q: 2048x1024 f32
#define K_OFF   (Q_OFF + (size_t)T_ITEM*DMODEL*4)    // k: 2176x1024 f32
#define V_OFF   (K_OFF + (size_t)T_INT*DMODEL*4)     // v: 2176x1024 f32
#define CNT_OFF (V_OFF + (size_t)T_INT*DMODEL*4)     // counts: 18 ints
#define LI_OFF  (CNT_OFF + 128)                      // item lists 9x2048
#define LN_OFF  (LI_OFF + (size_t)NBUCK*T_ITEM*4)    // intent lists 9x2176
#define WS_NEED (LN_OFF + (size_t)NBUCK*T_INT*4)

// fp64 sidecar buffers live INSIDE the V region (used before v-GEMM writes it):
//   q0d: 2048*64 f64 row-major (1 MB), k0dT: 64 x 2176 f64 TRANSPOSED (1.1 MB)
#define Q0D_OFF V_OFF
#define K0D_OFF (V_OFF + (size_t)T_ITEM*64*8)

#define X_OUT_ELEMS ((size_t)BSZ*SEQLEN*DMODEL)      // 2,097,152
#define SIDX_ELEMS  ((size_t)BSZ*SEQLEN)             // 2048

__device__ __forceinline__ int clampi(int v, int lo, int hi) {
  return v < lo ? lo : (v > hi ? hi : v);
}

// ---------------------------------------------------------------------------
// Kernel 1: counting-sort tokens into buckets (order within bucket irrelevant)
// ---------------------------------------------------------------------------
__global__ void bucketize_kernel(const int* __restrict__ b_seq, const int* __restrict__ b_seq2,
                                 int* __restrict__ cnt, int* __restrict__ list_item,
                                 int* __restrict__ list_int) {
  int t = blockIdx.x * blockDim.x + threadIdx.x;
  if (t < T_ITEM) {
    int B = clampi(b_seq[t], 0, NBUCK - 1);
    int p = atomicAdd(&cnt[B], 1);
    if (p >= 0 && p < T_ITEM) list_item[B * T_ITEM + p] = t;
  }
  if (t < T_INT) {
    int B = clampi(b_seq2[t], 0, NBUCK - 1);
    int p = atomicAdd(&cnt[NBUCK + B], 1);
    if (p >= 0 && p < T_INT) list_int[B * T_INT + p] = t;
  }
}

// ---------------------------------------------------------------------------
// fp64 sidecar A (v2): head-0 projection for BOTH item and intent in one
// launch. One block (256 thr = 4 waves) per token; each wave accumulates a
// 256-long d-slice, partials reduced in LDS in fixed order (f64).
// ---------------------------------------------------------------------------
__global__ __launch_bounds__(256) void proj_head0_f64_v2(
    const float* __restrict__ item, const float* __restrict__ intent,
    const float* __restrict__ Wq, const float* __restrict__ Wk,
    const int* __restrict__ b_seq, const int* __restrict__ b_seq2,
    double* __restrict__ q0d, double* __restrict__ k0dT) {
  const int blk = blockIdx.x;
  const int wv = (int)threadIdx.x >> 6, lane = (int)threadIdx.x & 63;
  const float* X; const float* W; const int* bs; int tok; bool tr;
  if (blk < T_ITEM) { tok = blk;          X = item;   W = Wq; bs = b_seq;  tr = false; }
  else              { tok = blk - T_ITEM; X = intent; W = Wk; bs = b_seq2; tr = true; }
  const int B = clampi(bs[tok], 0, NBUCK - 1);
  const float* xr = X + (size_t)tok * DMODEL;
  const float* wb = W + (size_t)B * DMODEL * (NHEAD * DK) + lane;  // W[B][d][lane]
  double acc = 0.0;
  const int d0 = wv * 256;
  #pragma unroll 8
  for (int d = d0; d < d0 + 256; ++d)
    acc += (double)xr[d] * (double)wb[(size_t)d * (NHEAD * DK)];
  __shared__ double part[4][64];
  part[wv][lane] = acc;
  __syncthreads();
  if (wv == 0) {
    double s = ((part[0][lane] + part[1][lane]) + part[2][lane]) + part[3][lane];
    if (tr) k0dT[(size_t)lane * T_INT + tok] = s;
    else    q0d[(size_t)tok * 64 + lane] = s;
  }
}

// ---------------------------------------------------------------------------
// fp64 sidecar B (v2): 4 q-rows per block; coalesced K0T columns; exact
// first-occurrence argmax -> sIdx, aIdx (bitwise-stable vs v1).
// ---------------------------------------------------------------------------
#define AR 4
__global__ __launch_bounds__(256) void argmax_f64_v2(
    const double* __restrict__ Q0, const double* __restrict__ K0T,
    float* __restrict__ out_s, float* __restrict__ out_a) {
  const int n0 = blockIdx.x * AR;    // q-row base; b uniform within block
  const int b = n0 >> 10;
  const int t = (int)threadIdx.x;
  __shared__ double qs[AR][64];
  qs[t >> 6][t & 63] = Q0[(size_t)(n0 + (t >> 6)) * 64 + (t & 63)];
  __syncthreads();
  double v1[AR], v2[AR]; int i1[AR], i2[AR];
  #pragma unroll
  for (int r = 0; r < AR; ++r) {
    v1[r] = -1e300; i1[r] = 0x7FFFFFFF;
    v2[r] = -1e300; i2[r] = 0x7FFFFFFF;
  }
  for (int m = t; m < NN2; m += 256) {
    const double* base = K0T + (size_t)b * NN2 + m;   // column m of K0T
    double s0 = 0.0, s1 = 0.0, s2 = 0.0, s3 = 0.0;
    #pragma unroll 8
    for (int k = 0; k < 64; ++k) {
      const double kv = base[(size_t)k * T_INT];
      s0 += qs[0][k] * kv; s1 += qs[1][k] * kv;
      s2 += qs[2][k] * kv; s3 += qs[3][k] * kv;
    }
    const double ss[AR] = {s0, s1, s2, s3};
    #pragma unroll
    for (int r = 0; r < AR; ++r) {
      const double s = ss[r];
      if (m < 1024) { if (s > v1[r] || (s == v1[r] && m < i1[r])) { v1[r] = s; i1[r] = m; } }
      else          { if (s > v2[r] || (s == v2[r] && m < i2[r])) { v2[r] = s; i2[r] = m; } }
    }
  }
  __shared__ double bval[256];  __shared__ int bidx[256];
  __shared__ double bval2[256]; __shared__ int bidx2[256];
  for (int r = 0; r < AR; ++r) {
    __syncthreads();
    bval[t] = v1[r]; bidx[t] = i1[r]; bval2[t] = v2[r]; bidx2[t] = i2[r];
    __syncthreads();
    for (int off = 128; off >= 1; off >>= 1) {
      if (t < off) {
        if (bval[t+off] >  bval[t] || (bval[t+off] ==  bval[t] &&  bidx[t+off] <  bidx[t])) { bval[t]  = bval[t+off];  bidx[t]  = bidx[t+off]; }
        if (bval2[t+off] > bval2[t] || (bval2[t+off] == bval2[t] && bidx2[t+off] < bidx2[t])) { bval2[t] = bval2[t+off]; bidx2[t] = bidx2[t+off]; }
      }
      __syncthreads();
    }
    if (t == 0) {
      out_s[n0 + r] = (float)bidx[0];
      out_a[n0 + r] = (float)(bidx2[0] - 1024);
    }
  }
}

// ---------------------------------------------------------------------------
// Kernel 2: FUSED grouped GEMM (v3): tile 128x128, 256 threads, 8x8 micro,
// register double-buffer prefetch.
// LDS ratio: 4 ds_read_b128 per 64 FMAs (4 FMA/float, was 2.67) -> the
// shared per-CU LDS pipe stops being the bound (R5 est. LDS 2.4x VALU).
// Per-output FMA order (k0 asc, kk asc) unchanged -> bitwise-identical Y.
// ---------------------------------------------------------------------------
#define GTM 128
#define GTN 128
#define GBK 16

__global__ __launch_bounds__(256) void gemm_grouped_fused(
    const float* __restrict__ item, const float* __restrict__ intent,
    const float* __restrict__ Wq, const float* __restrict__ Wk,
    const float* __restrict__ Wv,
    const int* __restrict__ list_item, const int* __restrict__ list_int,
    const int* __restrict__ cnt,
    float* __restrict__ qb, float* __restrict__ kb, float* __restrict__ vb) {
  const int z = blockIdx.z;
  const int g = z / 9, B = z - g * 9;
  const float* X;  const float* W;  const int* list;  float* Y;  int n, Tmax;
  if (g == 0)      { X = item;   W = Wq; list = list_item; Y = qb; n = min(cnt[B], T_ITEM);        Tmax = T_ITEM; }
  else if (g == 1) { X = intent; W = Wk; list = list_int;  Y = kb; n = min(cnt[NBUCK + B], T_INT); Tmax = T_INT; }
  else             { X = intent; W = Wv; list = list_int;  Y = vb; n = min(cnt[NBUCK + B], T_INT); Tmax = T_INT; }

  const int row0 = blockIdx.y * GTM;
  if (row0 >= n) return;                 // uniform across block
  const int rows = min(GTM, n - row0);
  const int c0 = blockIdx.x * GTN;
  const int t = (int)threadIdx.x;

  __shared__ float Xs[GBK][GTM + 4];   // k-major (transposed on store)
  __shared__ float Ws[GBK][GTN + 4];

  const int tokA = t >> 1;            // 0..127
  const int kqA  = (t & 1) * 8;       // 0 or 8
  const int liA  = clampi(list[row0 + min(tokA, rows - 1)], 0, Tmax - 1);
  const float* xrow = X + (size_t)liA * DMODEL;
  const int kW = t >> 4;              // 0..15
  const int cW = (t & 15) * 8;        // 0..120
  const float* wbase = W + ((size_t)B * DMODEL + kW) * (size_t)(NHEAD * DK) + c0 + cW;

  const int ty = t >> 4;              // 0..15 -> rows ty*8..+7
  const int tx = t & 15;              // 0..15 -> cols tx*8..+7

  float acc[8][8];
  #pragma unroll
  for (int i = 0; i < 8; ++i)
    #pragma unroll
    for (int j = 0; j < 8; ++j) acc[i][j] = 0.f;

  // prefetch k0 = 0
  float4 xa = *(const float4*)(xrow + kqA);
  float4 xb = *(const float4*)(xrow + kqA + 4);
  float4 wa = *(const float4*)wbase;
  float4 wc = *(const float4*)(wbase + 4);

  for (int k0 = 0; k0 < DMODEL; k0 += GBK) {
    __syncthreads();                       // previous tile fully consumed
    Xs[kqA + 0][tokA] = xa.x; Xs[kqA + 1][tokA] = xa.y;
    Xs[kqA + 2][tokA] = xa.z; Xs[kqA + 3][tokA] = xa.w;
    Xs[kqA + 4][tokA] = xb.x; Xs[kqA + 5][tokA] = xb.y;
    Xs[kqA + 6][tokA] = xb.z; Xs[kqA + 7][tokA] = xb.w;
    *(float4*)&Ws[kW][cW]     = wa;
    *(float4*)&Ws[kW][cW + 4] = wc;
    __syncthreads();

    if (k0 + GBK < DMODEL) {               // issue next tile's loads now;
      xa = *(const float4*)(xrow + k0 + GBK + kqA);       // waited at NEXT
      xb = *(const float4*)(xrow + k0 + GBK + kqA + 4);   // store -> hidden
      wa = *(const float4*)(wbase + (size_t)(k0 + GBK) * (NHEAD * DK));
      wc = *(const float4*)(wbase + (size_t)(k0 + GBK) * (NHEAD * DK) + 4);
    }

    #pragma unroll
    for (int kk = 0; kk < GBK; ++kk) {
      float a[8], bv[8];
      *(float4*)&a[0]  = *(const float4*)&Xs[kk][ty * 8];
      *(float4*)&a[4]  = *(const float4*)&Xs[kk][ty * 8 + 4];
      *(float4*)&bv[0] = *(const float4*)&Ws[kk][tx * 8];
      *(float4*)&bv[4] = *(const float4*)&Ws[kk][tx * 8 + 4];
      #pragma unroll
      for (int i = 0; i < 8; ++i)
        #pragma unroll
        for (int j = 0; j < 8; ++j)
          acc[i][j] = fmaf(a[i], bv[j], acc[i][j]);
    }
  }

  #pragma unroll
  for (int i = 0; i < 8; ++i) {
    const int r = ty * 8 + i;
    if (r < rows) {
      const int tok = clampi(list[row0 + r], 0, Tmax - 1);
      float* yr = Y + (size_t)tok * (size_t)(NHEAD * DK) + c0 + tx * 8;
      *(float4*)yr       = make_float4(acc[i][0], acc[i][1], acc[i][2], acc[i][3]);
      *(float4*)(yr + 4) = make_float4(acc[i][4], acc[i][5], acc[i][6], acc[i][7]);
    }
  }
}

// ---------------------------------------------------------------------------
// Kernel 3: fused attention. v3: THREE key-chunks per Ks pass (Ks[192][68],
// 60.4 KB static LDS — stays under the 64 KB limit). The 4 wave-uniform q
// ds_read_b128 per k4-step now feed 48 FMAs (was 32). Per-wave LDS b128 ops
// ~920 -> ~724; barriers 9 -> 6. Layout: 5 passes x 3 chunks (keys 0..959)
// + final 2-chunk pass (keys 960..1087). FMA order per score unchanged ->
// bitwise-identical output.
// ---------------------------------------------------------------------------
__device__ __forceinline__ unsigned ordf(float v) {
  unsigned s = __float_as_uint(v);
  return s ^ ((unsigned)((int)s >> 31) | 0x80000000u);
}
__device__ __forceinline__ float unordf(unsigned u) {
  unsigned s = (u & 0x80000000u) ? (u ^ 0x80000000u) : ~u;
  return __uint_as_float(s);
}
__device__ __forceinline__ unsigned long long shfl_xor_u64(unsigned long long w, int off) {
  unsigned lo = __shfl_xor((unsigned)w, off);
  unsigned hi = __shfl_xor((unsigned)(w >> 32), off);
  return ((unsigned long long)hi << 32) | lo;
}

__global__ __launch_bounds__(256) void attn_kernel(
    const float* __restrict__ Q, const float* __restrict__ K,
    const float* __restrict__ V, float* __restrict__ outx) {
  const int b = blockIdx.z, h = blockIdx.y;
  const int n0 = blockIdx.x * 16;
  const int t = (int)threadIdx.x;
  const int wave = t >> 6, lane = t & 63;

  __shared__ float Qs[16][64];
  __shared__ float Ks[192][68];       // 3 chunks; +4 pad: conflict-free b128
  __shared__ int   kept_m[16][32];
  __shared__ float kept_p[16][32];

  {
    const int r = t >> 4, k4 = (t & 15) * 4;
    *(float4*)&Qs[r][k4] =
        *(const float4*)(Q + (size_t)(b * SEQLEN + n0 + r) * (NHEAD * DK) + h * DK + k4);
  }
  __syncthreads();

  const int r0 = wave * 4;
  float sv[4][17];                    // static-indexed (unrolled loops only)

  // ---- passes 0..4: stage 192 key rows, score 3 chunks each ----
  #pragma unroll
  for (int p = 0; p < 5; ++p) {
    if (p > 0) __syncthreads();
    #pragma unroll
    for (int j = 0; j < 12; ++j) {
      const int row = (t >> 4) + 16 * j;          // 0..191
      const int k4 = (t & 15) * 4;
      *(float4*)&Ks[row][k4] =
          *(const float4*)(K + (size_t)(b * NN2 + p * 192 + row) * (NHEAD * DK) + h * DK + k4);
    }
    __syncthreads();

    float a0[3], a1[3], a2[3], a3[3];
    #pragma unroll
    for (int c = 0; c < 3; ++c) { a0[c] = 0.f; a1[c] = 0.f; a2[c] = 0.f; a3[c] = 0.f; }
    #pragma unroll 4
    for (int k4 = 0; k4 < 64; k4 += 4) {
      float4 kc[3];
      kc[0] = *(const float4*)&Ks[lane][k4];
      kc[1] = *(const float4*)&Ks[64 + lane][k4];
      kc[2] = *(const float4*)&Ks[128 + lane][k4];
      const float4 q0 = *(const float4*)&Qs[r0 + 0][k4];   // wave-uniform: LDS broadcast
      const float4 q1 = *(const float4*)&Qs[r0 + 1][k4];
      const float4 q2 = *(const float4*)&Qs[r0 + 2][k4];
      const float4 q3 = *(const float4*)&Qs[r0 + 3][k4];
      #pragma unroll
      for (int c = 0; c < 3; ++c) {
        a0[c] = fmaf(q0.x, kc[c].x, a0[c]); a0[c] = fmaf(q0.y, kc[c].y, a0[c]);
        a0[c] = fmaf(q0.z, kc[c].z, a0[c]); a0[c] = fmaf(q0.w, kc[c].w, a0[c]);
        a1[c] = fmaf(q1.x, kc[c].x, a1[c]); a1[c] = fmaf(q1.y, kc[c].y, a1[c]);
        a1[c] = fmaf(q1.z, kc[c].z, a1[c]); a1[c] = fmaf(q1.w, kc[c].w, a1[c]);
        a2[c] = fmaf(q2.x, kc[c].x, a2[c]); a2[c] = fmaf(q2.y, kc[c].y, a2[c]);
        a2[c] = fmaf(q2.z, kc[c].z, a2[c]); a2[c] = fmaf(q2.w, kc[c].w, a2[c]);
        a3[c] = fmaf(q3.x, kc[c].x, a3[c]); a3[c] = fmaf(q3.y, kc[c].y, a3[c]);
        a3[c] = fmaf(q3.z, kc[c].z, a3[c]); a3[c] = fmaf(q3.w, kc[c].w, a3[c]);
      }
    }
    #pragma unroll
    for (int c = 0; c < 3; ++c) {
      sv[0][3 * p + c] = a0[c] * 0.125f; sv[1][3 * p + c] = a1[c] * 0.125f;
      sv[2][3 * p + c] = a2[c] * 0.125f; sv[3][3 * p + c] = a3[c] * 0.125f;
    }
  }

  // ---- final pass: keys 960..1087 (chunk 15 + NI tail chunk 16) ----
  {
    __syncthreads();
    #pragma unroll
    for (int j = 0; j < 8; ++j) {
      const int row = (t >> 4) + 16 * j;          // 0..127
      const int k4 = (t & 15) * 4;
      *(float4*)&Ks[row][k4] =
          *(const float4*)(K + (size_t)(b * NN2 + 960 + row) * (NHEAD * DK) + h * DK + k4);
    }
    __syncthreads();

    float a0[2], a1[2], a2[2], a3[2];
    #pragma unroll
    for (int c = 0; c < 2; ++c) { a0[c] = 0.f; a1[c] = 0.f; a2[c] = 0.f; a3[c] = 0.f; }
    #pragma unroll 4
    for (int k4 = 0; k4 < 64; k4 += 4) {
      float4 kc[2];
      kc[0] = *(const float4*)&Ks[lane][k4];
      kc[1] = *(const float4*)&Ks[64 + lane][k4];
      const float4 q0 = *(const float4*)&Qs[r0 + 0][k4];
      const float4 q1 = *(const float4*)&Qs[r0 + 1][k4];
      const float4 q2 = *(const float4*)&Qs[r0 + 2][k4];
      const float4 q3 = *(const float4*)&Qs[r0 + 3][k4];
      #pragma unroll
      for (int c = 0; c < 2; ++c) {
        a0[c] = fmaf(q0.x, kc[c].x, a0[c]); a0[c] = fmaf(q0.y, kc[c].y, a0[c]);
        a0[c] = fmaf(q0.z, kc[c].z, a0[c]); a0[c] = fmaf(q0.w, kc[c].w, a0[c]);
        a1[c] = fmaf(q1.x, kc[c].x, a1[c]); a1[c] = fmaf(q1.y, kc[c].y, a1[c]);
        a1[c] = fmaf(q1.z, kc[c].z, a1[c]); a1[c] = fmaf(q1.w, kc[c].w, a1[c]);
        a2[c] = fmaf(q2.x, kc[c].x, a2[c]); a2[c] = fmaf(q2.y, kc[c].y, a2[c]);
        a2[c] = fmaf(q2.z, kc[c].z, a2[c]); a2[c] = fmaf(q2.w, kc[c].w, a2[c]);
        a3[c] = fmaf(q3.x, kc[c].x, a3[c]); a3[c] = fmaf(q3.y, kc[c].y, a3[c]);
        a3[c] = fmaf(q3.z, kc[c].z, a3[c]); a3[c] = fmaf(q3.w, kc[c].w, a3[c]);
      }
    }
    #pragma unroll
    for (int c = 0; c < 2; ++c) {
      sv[0][15 + c] = a0[c] * 0.125f; sv[1][15 + c] = a1[c] * 0.125f;
      sv[2][15 + c] = a2[c] * 0.125f; sv[3][15 + c] = a3[c] * 0.125f;
    }
  }

  // ---- softmax stats, 4 rows interleaved ----
  float M_[4], invL_[4];
  {
    float L_[4];
    #pragma unroll
    for (int r = 0; r < 4; ++r) {
      float M = -3.402823466e38f;
      #pragma unroll
      for (int c = 0; c < 17; ++c) M = fmaxf(M, sv[r][c]);
      M_[r] = M;
    }
    #pragma unroll
    for (int off = 32; off >= 1; off >>= 1) {
      #pragma unroll
      for (int r = 0; r < 4; ++r) M_[r] = fmaxf(M_[r], __shfl_xor(M_[r], off));
    }
    #pragma unroll
    for (int r = 0; r < 4; ++r) {
      float L = 0.f;
      #pragma unroll
      for (int c = 0; c < 17; ++c) L += __expf(sv[r][c] - M_[r]);
      L_[r] = L;
    }
    #pragma unroll
    for (int off = 32; off >= 1; off >>= 1) {
      #pragma unroll
      for (int r = 0; r < 4; ++r) L_[r] += __shfl_xor(L_[r], off);
    }
    #pragma unroll
    for (int r = 0; r < 4; ++r) invL_[r] = 1.0f / L_[r];
  }

  // ---- segment 1 keys + per-lane top-2 init ----
  unsigned kh[4][16];
  #pragma unroll
  for (int r = 0; r < 4; ++r)
    #pragma unroll
    for (int c = 0; c < 16; ++c) kh[r][c] = ordf(sv[r][c]);

  unsigned long long b1_[4], b2_[4];
  unsigned alive_[4];
  #pragma unroll
  for (int r = 0; r < 4; ++r) {
    unsigned long long b1 = 0ull, b2 = 0ull;
    #pragma unroll
    for (int c = 0; c < 16; ++c) {
      const unsigned long long k64 =
          ((unsigned long long)kh[r][c] << 32) | (unsigned)~(unsigned)(c * 64 + lane);
      const unsigned long long mn = (k64 < b1) ? k64 : b1;  // min(b1,k)
      b1 = (k64 > b1) ? k64 : b1;
      b2 = (mn > b2) ? mn : b2;
    }
    b1_[r] = b1; b2_[r] = b2; alive_[r] = 0xFFFFu;
  }

  // ---- segment 1: 16 extraction rounds, 4 rows interleaved ----
  for (int round = 0; round < TOPK; ++round) {
    unsigned long long w0 = b1_[0], w1 = b1_[1], w2 = b1_[2], w3 = b1_[3];
    #pragma unroll
    for (int off = 1; off < 64; off <<= 1) {
      unsigned long long o;
      o = shfl_xor_u64(w0, off); w0 = (o > w0) ? o : w0;
      o = shfl_xor_u64(w1, off); w1 = (o > w1) ? o : w1;
      o = shfl_xor_u64(w2, off); w2 = (o > w2) ? o : w2;
      o = shfl_xor_u64(w3, off); w3 = (o > w3) ? o : w3;
    }
    const unsigned long long ws[4] = {w0, w1, w2, w3};
    #pragma unroll
    for (int r = 0; r < 4; ++r) {
      const unsigned long long w = ws[r];
      const int m = (int)((~(unsigned)w) & 1023u);
      if (lane == round) {
        kept_m[r0 + r][round] = m;
        kept_p[r0 + r][round] = __expf(unordf((unsigned)(w >> 32)) - M_[r]) * invL_[r];
      }
      if ((m & 63) == lane) {          // winner lane bookkeeping
        alive_[r] &= ~(1u << (m >> 6));
        if (b2_[r]) { b1_[r] = b2_[r]; b2_[r] = 0ull; }
        else {
          unsigned long long mx = 0ull;
          #pragma unroll
          for (int c = 0; c < 16; ++c) {
            const unsigned long long k64 =
                ((unsigned long long)kh[r][c] << 32) | (unsigned)~(unsigned)(c * 64 + lane);
            if ((alive_[r] >> c) & 1u) mx = (k64 > mx) ? k64 : mx;
          }
          b1_[r] = mx;
        }
      }
    }
  }

  // ---- segment 2: bitonic sort (descending) of the 64 tail candidates ----
  {
    unsigned long long w_[4];
    #pragma unroll
    for (int r = 0; r < 4; ++r)
      w_[r] = ((unsigned long long)ordf(sv[r][16]) << 32) | (unsigned)~(unsigned)lane;
    #pragma unroll
    for (int k = 2; k <= 64; k <<= 1) {
      #pragma unroll
      for (int j = k >> 1; j >= 1; j >>= 1) {
        const bool tm = (((lane & j) != 0) == ((lane & k) != 0));
        #pragma unroll
        for (int r = 0; r < 4; ++r) {
          const unsigned long long o = shfl_xor_u64(w_[r], j);
          w_[r] = ((o > w_[r]) == tm) ? o : w_[r];
        }
      }
    }
    if (lane < TOPK) {
      #pragma unroll
      for (int r = 0; r < 4; ++r) {
        kept_m[r0 + r][TOPK + lane] = 1024 + (int)((~(unsigned)w_[r]) & 63u);
        kept_p[r0 + r][TOPK + lane] =
            __expf(unordf((unsigned)(w_[r] >> 32)) - M_[r]) * invL_[r];
      }
    }
  }
  __syncthreads();

  #pragma unroll
  for (int rr = 0; rr < 4; ++rr) {
    const int r_loc = wave * 4 + rr;
    const int n = n0 + r_loc;
    float x = 0.f;
    #pragma unroll
    for (int i = 0; i < 32; ++i) {
      const int m = clampi(kept_m[r_loc][i], 0, NN2 - 1);
      const float p = kept_p[r_loc][i];
      x = fmaf(p, V[(size_t)(b * NN2 + m) * (NHEAD * DK) + h * DK + lane], x);
    }
    outx[(size_t)(b * SEQLEN + n) * (NHEAD * DK) + h * DK + lane] = x;
  }
}

// ---------------------------------------------------------------------------
extern "C" void kernel_launch(void* const* d_in, const int* in_sizes, int n_in,
                              void* d_out, int out_size, void* d_ws, size_t ws_size,
                              hipStream_t stream) {
  const float* item    = (const float*)d_in[0];
  const float* intent  = (const float*)d_in[1];
  // d_in[2] = mask: constant all-True -> no-op, skipped
  const int*   b_seq   = (const int*)d_in[3];
  const int*   b_seq2  = (const int*)d_in[4];
  const float* W_item  = (const float*)d_in[5];   // [9][1024][16][64]
  const float* W_int   = (const float*)d_in[6];   // [2][9][1024][16][64]

  if (ws_size < WS_NEED) return;   // clean failure instead of device fault

  char* ws = (char*)d_ws;
  float* qb = (float*)(ws + Q_OFF);
  float* kb = (float*)(ws + K_OFF);
  float* vb = (float*)(ws + V_OFF);
  double* q0d = (double*)(ws + Q0D_OFF);   // aliases V region (used before v-GEMM)
  double* k0dT = (double*)(ws + K0D_OFF);  // transposed [64][T_INT]
  int* cnt       = (int*)(ws + CNT_OFF);
  int* list_item = (int*)(ws + LI_OFF);
  int* list_int  = (int*)(ws + LN_OFF);

  float* outx  = (float*)d_out;
  float* out_s = outx + X_OUT_ELEMS;
  float* out_a = out_s + SIDX_ELEMS;

  hipMemsetAsync(cnt, 0, 128, stream);
  bucketize_kernel<<<dim3(9), 256, 0, stream>>>(b_seq, b_seq2, cnt, list_item, list_int);

  // fp64 sidecar: fused head-0 q/k projections (one launch) + 4-row argmax.
  proj_head0_f64_v2<<<dim3(T_ITEM + T_INT), 256, 0, stream>>>(
      item, intent, W_item, W_int, b_seq, b_seq2, q0d, k0dT);
  argmax_f64_v2<<<dim3(T_ITEM / AR), 256, 0, stream>>>(q0d, k0dT, out_s, out_a);

  // fused fp32 q/k/v grouped GEMM (runs after argmax; v-write aliases sidecar)
  gemm_grouped_fused<<<dim3((NHEAD * DK) / GTN, 17, 27), 256, 0, stream>>>(
      item, intent,
      W_item, W_int, W_int + (size_t)NBUCK * DMODEL * (NHEAD * DK),
      list_item, list_int, cnt, qb, kb, vb);

  attn_kernel<<<dim3(SEQLEN / 16, NHEAD, BSZ), 256, 0, stream>>>(qb, kb, vb, outx);
}

// Round 7
// 691.847 us; speedup vs baseline: 1.6744x; 1.0251x over previous
//
#include <hip/hip_runtime.h>

// Problem constants (match reference)
#define NHEAD   16
#define DK      64
#define DMODEL  1024
#define BSZ     2
#define SEQLEN  1024
#define NI      64
#define NN2     1088          // SEQLEN + NI
#define NBUCK   9             // N_B + 1
#define TOPK    16

#define T_ITEM  (BSZ*SEQLEN)  // 2048 item tokens
#define T_INT   (BSZ*NN2)     // 2176 intent tokens

// workspace layout (bytes). base ~26.4 MB; +26.2 MB partials if available
#define Q_OFF   ((size_t)0)                          // q: 2048x1024 f32
#define K_OFF   (Q_OFF + (size_t)T_ITEM*DMODEL*4)    // k: 2176x1024 f32
#define V_OFF   (K_OFF + (size_t)T_INT*DMODEL*4)     // v: 2176x1024 f32
#define QKV_BYTES (V_OFF + (size_t)T_INT*DMODEL*4)   // contiguous q|k|v size
#define CNT_OFF QKV_BYTES                            // counts: 18 ints
#define LI_OFF  (CNT_OFF + 128)                      // item lists 9x2048
#define LN_OFF  (LI_OFF + (size_t)NBUCK*T_ITEM*4)    // intent lists 9x2176
#define WS_NEED (LN_OFF + (size_t)NBUCK*T_INT*4)
// split-K partial region (mirror of q|k|v), optional:
#define P_OFF   ((WS_NEED + 255) & ~(size_t)255)
#define WS_NEED2 (P_OFF + QKV_BYTES)

// fp64 sidecar buffers live INSIDE the V region (used before v-GEMM writes it):
//   q0d: 2048*64 f64 row-major (1 MB), k0dT: 64 x 2176 f64 TRANSPOSED (1.1 MB)
#define Q0D_OFF V_OFF
#define K0D_OFF (V_OFF + (size_t)T_ITEM*64*8)

#define X_OUT_ELEMS ((size_t)BSZ*SEQLEN*DMODEL)      // 2,097,152
#define SIDX_ELEMS  ((size_t)BSZ*SEQLEN)             // 2048

__device__ __forceinline__ int clampi(int v, int lo, int hi) {
  return v < lo ? lo : (v > hi ? hi : v);
}

// ---------------------------------------------------------------------------
// Kernel 1: counting-sort tokens into buckets (order within bucket irrelevant)
// ---------------------------------------------------------------------------
__global__ void bucketize_kernel(const int* __restrict__ b_seq, const int* __restrict__ b_seq2,
                                 int* __restrict__ cnt, int* __restrict__ list_item,
                                 int* __restrict__ list_int) {
  int t = blockIdx.x * blockDim.x + threadIdx.x;
  if (t < T_ITEM) {
    int B = clampi(b_seq[t], 0, NBUCK - 1);
    int p = atomicAdd(&cnt[B], 1);
    if (p >= 0 && p < T_ITEM) list_item[B * T_ITEM + p] = t;
  }
  if (t < T_INT) {
    int B = clampi(b_seq2[t], 0, NBUCK - 1);
    int p = atomicAdd(&cnt[NBUCK + B], 1);
    if (p >= 0 && p < T_INT) list_int[B * T_INT + p] = t;
  }
}

// ---------------------------------------------------------------------------
// fp64 sidecar A (v2): head-0 projection for BOTH item and intent in one
// launch. One block (256 thr = 4 waves) per token; each wave accumulates a
// 256-long d-slice, partials reduced in LDS in fixed order (f64).
// ---------------------------------------------------------------------------
__global__ __launch_bounds__(256) void proj_head0_f64_v2(
    const float* __restrict__ item, const float* __restrict__ intent,
    const float* __restrict__ Wq, const float* __restrict__ Wk,
    const int* __restrict__ b_seq, const int* __restrict__ b_seq2,
    double* __restrict__ q0d, double* __restrict__ k0dT) {
  const int blk = blockIdx.x;
  const int wv = (int)threadIdx.x >> 6, lane = (int)threadIdx.x & 63;
  const float* X; const float* W; const int* bs; int tok; bool tr;
  if (blk < T_ITEM) { tok = blk;          X = item;   W = Wq; bs = b_seq;  tr = false; }
  else              { tok = blk - T_ITEM; X = intent; W = Wk; bs = b_seq2; tr = true; }
  const int B = clampi(bs[tok], 0, NBUCK - 1);
  const float* xr = X + (size_t)tok * DMODEL;
  const float* wb = W + (size_t)B * DMODEL * (NHEAD * DK) + lane;  // W[B][d][lane]
  double acc = 0.0;
  const int d0 = wv * 256;
  #pragma unroll 8
  for (int d = d0; d < d0 + 256; ++d)
    acc += (double)xr[d] * (double)wb[(size_t)d * (NHEAD * DK)];
  __shared__ double part[4][64];
  part[wv][lane] = acc;
  __syncthreads();
  if (wv == 0) {
    double s = ((part[0][lane] + part[1][lane]) + part[2][lane]) + part[3][lane];
    if (tr) k0dT[(size_t)lane * T_INT + tok] = s;
    else    q0d[(size_t)tok * 64 + lane] = s;
  }
}

// ---------------------------------------------------------------------------
// fp64 sidecar B (v2): 4 q-rows per block; coalesced K0T columns; exact
// first-occurrence argmax -> sIdx, aIdx.
// ---------------------------------------------------------------------------
#define AR 4
__global__ __launch_bounds__(256) void argmax_f64_v2(
    const double* __restrict__ Q0, const double* __restrict__ K0T,
    float* __restrict__ out_s, float* __restrict__ out_a) {
  const int n0 = blockIdx.x * AR;    // q-row base; b uniform within block
  const int b = n0 >> 10;
  const int t = (int)threadIdx.x;
  __shared__ double qs[AR][64];
  qs[t >> 6][t & 63] = Q0[(size_t)(n0 + (t >> 6)) * 64 + (t & 63)];
  __syncthreads();
  double v1[AR], v2[AR]; int i1[AR], i2[AR];
  #pragma unroll
  for (int r = 0; r < AR; ++r) {
    v1[r] = -1e300; i1[r] = 0x7FFFFFFF;
    v2[r] = -1e300; i2[r] = 0x7FFFFFFF;
  }
  for (int m = t; m < NN2; m += 256) {
    const double* base = K0T + (size_t)b * NN2 + m;   // column m of K0T
    double s0 = 0.0, s1 = 0.0, s2 = 0.0, s3 = 0.0;
    #pragma unroll 8
    for (int k = 0; k < 64; ++k) {
      const double kv = base[(size_t)k * T_INT];
      s0 += qs[0][k] * kv; s1 += qs[1][k] * kv;
      s2 += qs[2][k] * kv; s3 += qs[3][k] * kv;
    }
    const double ss[AR] = {s0, s1, s2, s3};
    #pragma unroll
    for (int r = 0; r < AR; ++r) {
      const double s = ss[r];
      if (m < 1024) { if (s > v1[r] || (s == v1[r] && m < i1[r])) { v1[r] = s; i1[r] = m; } }
      else          { if (s > v2[r] || (s == v2[r] && m < i2[r])) { v2[r] = s; i2[r] = m; } }
    }
  }
  __shared__ double bval[256];  __shared__ int bidx[256];
  __shared__ double bval2[256]; __shared__ int bidx2[256];
  for (int r = 0; r < AR; ++r) {
    __syncthreads();
    bval[t] = v1[r]; bidx[t] = i1[r]; bval2[t] = v2[r]; bidx2[t] = i2[r];
    __syncthreads();
    for (int off = 128; off >= 1; off >>= 1) {
      if (t < off) {
        if (bval[t+off] >  bval[t] || (bval[t+off] ==  bval[t] &&  bidx[t+off] <  bidx[t])) { bval[t]  = bval[t+off];  bidx[t]  = bidx[t+off]; }
        if (bval2[t+off] > bval2[t] || (bval2[t+off] == bval2[t] && bidx2[t+off] < bidx2[t])) { bval2[t] = bval2[t+off]; bidx2[t] = bidx2[t+off]; }
      }
      __syncthreads();
    }
    if (t == 0) {
      out_s[n0 + r] = (float)bidx[0];
      out_a[n0 + r] = (float)(bidx2[0] - 1024);
    }
  }
}

// ---------------------------------------------------------------------------
// Kernel 2: FUSED grouped GEMM (v4): tile 128x128, 256 thr, 8x8 micro,
// register prefetch, CONFLICT-FREE column mapping, optional split-K=2.
//  * bank fix (measured 1.9e7 conflicts in v3): thread columns are two
//    stride-4 groups {tx*4, 64+tx*4} instead of one stride-8 group tx*8.
//    16 lanes at word-stride 4 cover all 32 banks (2-way alias = free);
//    stride-8 put 4 lanes on the same 4-bank group (4-way, 1.58x).
//  * split-K: z = s*27 + g*9 + B; s=0 writes Y, s=1 writes partial P;
//    reduce_add does Y += P in fixed order (deterministic 2-addend sum).
//    ~800 active blocks (~3/CU) removes the 1.56-block/CU grid tail.
// Per-output k-order within each half unchanged (k0 asc, kk asc).
// ---------------------------------------------------------------------------
#define GTM 128
#define GTN 128
#define GBK 16

__global__ __launch_bounds__(256) void gemm_grouped_fused(
    const float* __restrict__ item, const float* __restrict__ intent,
    const float* __restrict__ Wq, const float* __restrict__ Wk,
    const float* __restrict__ Wv,
    const int* __restrict__ list_item, const int* __restrict__ list_int,
    const int* __restrict__ cnt,
    float* __restrict__ qb, float* __restrict__ kb, float* __restrict__ vb,
    float* __restrict__ pq, float* __restrict__ pk, float* __restrict__ pv,
    const int klen) {
  const int z = blockIdx.z;
  const int s = z / 27;                 // k-split index (0 when klen==1024)
  const int rem = z - s * 27;
  const int g = rem / 9, B = rem - g * 9;
  const int kbeg = s * klen;
  const float* X;  const float* W;  const int* list;  float* Y;  int n, Tmax;
  if (g == 0)      { X = item;   W = Wq; list = list_item; Y = s ? pq : qb; n = min(cnt[B], T_ITEM);        Tmax = T_ITEM; }
  else if (g == 1) { X = intent; W = Wk; list = list_int;  Y = s ? pk : kb; n = min(cnt[NBUCK + B], T_INT); Tmax = T_INT; }
  else             { X = intent; W = Wv; list = list_int;  Y = s ? pv : vb; n = min(cnt[NBUCK + B], T_INT); Tmax = T_INT; }

  const int row0 = blockIdx.y * GTM;
  if (row0 >= n) return;                 // uniform across block
  const int rows = min(GTM, n - row0);
  const int c0 = blockIdx.x * GTN;
  const int t = (int)threadIdx.x;

  __shared__ float Xs[GBK][GTM + 4];   // k-major (transposed on store)
  __shared__ float Ws[GBK][GTN];       // stride-4 col groups: conflict-free

  const int tokA = t >> 1;            // 0..127
  const int kqA  = (t & 1) * 8;       // 0 or 8
  const int liA  = clampi(list[row0 + min(tokA, rows - 1)], 0, Tmax - 1);
  const float* xrow = X + (size_t)liA * DMODEL;
  const int kW  = t >> 4;             // 0..15
  const int cW  = (t & 15) * 4;       // 0..60 (stride-4: banks spread)
  const float* wbase = W + ((size_t)B * DMODEL + kW) * (size_t)(NHEAD * DK) + c0 + cW;

  const int ty = t >> 4;              // 0..15 -> rows ty*8..+7
  const int tx = t & 15;              // 0..15 -> cols {tx*4..+3, 64+tx*4..+3}

  float acc[8][8];
  #pragma unroll
  for (int i = 0; i < 8; ++i)
    #pragma unroll
    for (int j = 0; j < 8; ++j) acc[i][j] = 0.f;

  // prefetch first k-step
  float4 xa = *(const float4*)(xrow + kbeg + kqA);
  float4 xb = *(const float4*)(xrow + kbeg + kqA + 4);
  float4 wa = *(const float4*)(wbase + (size_t)kbeg * (NHEAD * DK));
  float4 wc = *(const float4*)(wbase + (size_t)kbeg * (NHEAD * DK) + 64);

  for (int k0 = kbeg; k0 < kbeg + klen; k0 += GBK) {
    __syncthreads();                       // previous tile fully consumed
    Xs[kqA + 0][tokA] = xa.x; Xs[kqA + 1][tokA] = xa.y;
    Xs[kqA + 2][tokA] = xa.z; Xs[kqA + 3][tokA] = xa.w;
    Xs[kqA + 4][tokA] = xb.x; Xs[kqA + 5][tokA] = xb.y;
    Xs[kqA + 6][tokA] = xb.z; Xs[kqA + 7][tokA] = xb.w;
    *(float4*)&Ws[kW][cW]      = wa;
    *(float4*)&Ws[kW][cW + 64] = wc;
    __syncthreads();

    if (k0 + GBK < kbeg + klen) {          // issue next tile's loads now
      xa = *(const float4*)(xrow + k0 + GBK + kqA);
      xb = *(const float4*)(xrow + k0 + GBK + kqA + 4);
      wa = *(const float4*)(wbase + (size_t)(k0 + GBK) * (NHEAD * DK));
      wc = *(const float4*)(wbase + (size_t)(k0 + GBK) * (NHEAD * DK) + 64);
    }

    #pragma unroll
    for (int kk = 0; kk < GBK; ++kk) {
      float a[8], bv[8];
      *(float4*)&a[0]  = *(const float4*)&Xs[kk][ty * 8];       // broadcast
      *(float4*)&a[4]  = *(const float4*)&Xs[kk][ty * 8 + 4];
      *(float4*)&bv[0] = *(const float4*)&Ws[kk][tx * 4];       // stride-4
      *(float4*)&bv[4] = *(const float4*)&Ws[kk][tx * 4 + 64];
      #pragma unroll
      for (int i = 0; i < 8; ++i)
        #pragma unroll
        for (int j = 0; j < 8; ++j)
          acc[i][j] = fmaf(a[i], bv[j], acc[i][j]);
    }
  }

  #pragma unroll
  for (int i = 0; i < 8; ++i) {
    const int r = ty * 8 + i;
    if (r < rows) {
      const int tok = clampi(list[row0 + r], 0, Tmax - 1);
      float* yr = Y + (size_t)tok * (size_t)(NHEAD * DK) + c0 + tx * 4;
      *(float4*)yr        = make_float4(acc[i][0], acc[i][1], acc[i][2], acc[i][3]);
      *(float4*)(yr + 64) = make_float4(acc[i][4], acc[i][5], acc[i][6], acc[i][7]);
    }
  }
}

// Y += P over the contiguous q|k|v region (fixed order: deterministic).
__global__ __launch_bounds__(256) void reduce_add(
    float4* __restrict__ y, const float4* __restrict__ p, const int n4) {
  const int stride = gridDim.x * blockDim.x;
  for (int i = blockIdx.x * blockDim.x + threadIdx.x; i < n4; i += stride) {
    float4 a = y[i]; const float4 b = p[i];
    a.x += b.x; a.y += b.y; a.z += b.z; a.w += b.w;
    y[i] = a;
  }
}

// ---------------------------------------------------------------------------
// Kernel 3: fused attention (unchanged from R6: 3-chunk Ks staging).
// ---------------------------------------------------------------------------
__device__ __forceinline__ unsigned ordf(float v) {
  unsigned s = __float_as_uint(v);
  return s ^ ((unsigned)((int)s >> 31) | 0x80000000u);
}
__device__ __forceinline__ float unordf(unsigned u) {
  unsigned s = (u & 0x80000000u) ? (u ^ 0x80000000u) : ~u;
  return __uint_as_float(s);
}
__device__ __forceinline__ unsigned long long shfl_xor_u64(unsigned long long w, int off) {
  unsigned lo = __shfl_xor((unsigned)w, off);
  unsigned hi = __shfl_xor((unsigned)(w >> 32), off);
  return ((unsigned long long)hi << 32) | lo;
}

__global__ __launch_bounds__(256) void attn_kernel(
    const float* __restrict__ Q, const float* __restrict__ K,
    const float* __restrict__ V, float* __restrict__ outx) {
  const int b = blockIdx.z, h = blockIdx.y;
  const int n0 = blockIdx.x * 16;
  const int t = (int)threadIdx.x;
  const int wave = t >> 6, lane = t & 63;

  __shared__ float Qs[16][64];
  __shared__ float Ks[192][68];       // 3 chunks; +4 pad: conflict-free b128
  __shared__ int   kept_m[16][32];
  __shared__ float kept_p[16][32];

  {
    const int r = t >> 4, k4 = (t & 15) * 4;
    *(float4*)&Qs[r][k4] =
        *(const float4*)(Q + (size_t)(b * SEQLEN + n0 + r) * (NHEAD * DK) + h * DK + k4);
  }
  __syncthreads();

  const int r0 = wave * 4;
  float sv[4][17];                    // static-indexed (unrolled loops only)

  // ---- passes 0..4: stage 192 key rows, score 3 chunks each ----
  #pragma unroll
  for (int p = 0; p < 5; ++p) {
    if (p > 0) __syncthreads();
    #pragma unroll
    for (int j = 0; j < 12; ++j) {
      const int row = (t >> 4) + 16 * j;          // 0..191
      const int k4 = (t & 15) * 4;
      *(float4*)&Ks[row][k4] =
          *(const float4*)(K + (size_t)(b * NN2 + p * 192 + row) * (NHEAD * DK) + h * DK + k4);
    }
    __syncthreads();

    float a0[3], a1[3], a2[3], a3[3];
    #pragma unroll
    for (int c = 0; c < 3; ++c) { a0[c] = 0.f; a1[c] = 0.f; a2[c] = 0.f; a3[c] = 0.f; }
    #pragma unroll 4
    for (int k4 = 0; k4 < 64; k4 += 4) {
      float4 kc[3];
      kc[0] = *(const float4*)&Ks[lane][k4];
      kc[1] = *(const float4*)&Ks[64 + lane][k4];
      kc[2] = *(const float4*)&Ks[128 + lane][k4];
      const float4 q0 = *(const float4*)&Qs[r0 + 0][k4];   // wave-uniform: LDS broadcast
      const float4 q1 = *(const float4*)&Qs[r0 + 1][k4];
      const float4 q2 = *(const float4*)&Qs[r0 + 2][k4];
      const float4 q3 = *(const float4*)&Qs[r0 + 3][k4];
      #pragma unroll
      for (int c = 0; c < 3; ++c) {
        a0[c] = fmaf(q0.x, kc[c].x, a0[c]); a0[c] = fmaf(q0.y, kc[c].y, a0[c]);
        a0[c] = fmaf(q0.z, kc[c].z, a0[c]); a0[c] = fmaf(q0.w, kc[c].w, a0[c]);
        a1[c] = fmaf(q1.x, kc[c].x, a1[c]); a1[c] = fmaf(q1.y, kc[c].y, a1[c]);
        a1[c] = fmaf(q1.z, kc[c].z, a1[c]); a1[c] = fmaf(q1.w, kc[c].w, a1[c]);
        a2[c] = fmaf(q2.x, kc[c].x, a2[c]); a2[c] = fmaf(q2.y, kc[c].y, a2[c]);
        a2[c] = fmaf(q2.z, kc[c].z, a2[c]); a2[c] = fmaf(q2.w, kc[c].w, a2[c]);
        a3[c] = fmaf(q3.x, kc[c].x, a3[c]); a3[c] = fmaf(q3.y, kc[c].y, a3[c]);
        a3[c] = fmaf(q3.z, kc[c].z, a3[c]); a3[c] = fmaf(q3.w, kc[c].w, a3[c]);
      }
    }
    #pragma unroll
    for (int c = 0; c < 3; ++c) {
      sv[0][3 * p + c] = a0[c] * 0.125f; sv[1][3 * p + c] = a1[c] * 0.125f;
      sv[2][3 * p + c] = a2[c] * 0.125f; sv[3][3 * p + c] = a3[c] * 0.125f;
    }
  }

  // ---- final pass: keys 960..1087 (chunk 15 + NI tail chunk 16) ----
  {
    __syncthreads();
    #pragma unroll
    for (int j = 0; j < 8; ++j) {
      const int row = (t >> 4) + 16 * j;          // 0..127
      const int k4 = (t & 15) * 4;
      *(float4*)&Ks[row][k4] =
          *(const float4*)(K + (size_t)(b * NN2 + 960 + row) * (NHEAD * DK) + h * DK + k4);
    }
    __syncthreads();

    float a0[2], a1[2], a2[2], a3[2];
    #pragma unroll
    for (int c = 0; c < 2; ++c) { a0[c] = 0.f; a1[c] = 0.f; a2[c] = 0.f; a3[c] = 0.f; }
    #pragma unroll 4
    for (int k4 = 0; k4 < 64; k4 += 4) {
      float4 kc[2];
      kc[0] = *(const float4*)&Ks[lane][k4];
      kc[1] = *(const float4*)&Ks[64 + lane][k4];
      const float4 q0 = *(const float4*)&Qs[r0 + 0][k4];
      const float4 q1 = *(const float4*)&Qs[r0 + 1][k4];
      const float4 q2 = *(const float4*)&Qs[r0 + 2][k4];
      const float4 q3 = *(const float4*)&Qs[r0 + 3][k4];
      #pragma unroll
      for (int c = 0; c < 2; ++c) {
        a0[c] = fmaf(q0.x, kc[c].x, a0[c]); a0[c] = fmaf(q0.y, kc[c].y, a0[c]);
        a0[c] = fmaf(q0.z, kc[c].z, a0[c]); a0[c] = fmaf(q0.w, kc[c].w, a0[c]);
        a1[c] = fmaf(q1.x, kc[c].x, a1[c]); a1[c] = fmaf(q1.y, kc[c].y, a1[c]);
        a1[c] = fmaf(q1.z, kc[c].z, a1[c]); a1[c] = fmaf(q1.w, kc[c].w, a1[c]);
        a2[c] = fmaf(q2.x, kc[c].x, a2[c]); a2[c] = fmaf(q2.y, kc[c].y, a2[c]);
        a2[c] = fmaf(q2.z, kc[c].z, a2[c]); a2[c] = fmaf(q2.w, kc[c].w, a2[c]);
        a3[c] = fmaf(q3.x, kc[c].x, a3[c]); a3[c] = fmaf(q3.y, kc[c].y, a3[c]);
        a3[c] = fmaf(q3.z, kc[c].z, a3[c]); a3[c] = fmaf(q3.w, kc[c].w, a3[c]);
      }
    }
    #pragma unroll
    for (int c = 0; c < 2; ++c) {
      sv[0][15 + c] = a0[c] * 0.125f; sv[1][15 + c] = a1[c] * 0.125f;
      sv[2][15 + c] = a2[c] * 0.125f; sv[3][15 + c] = a3[c] * 0.125f;
    }
  }

  // ---- softmax stats, 4 rows interleaved ----
  float M_[4], invL_[4];
  {
    float L_[4];
    #pragma unroll
    for (int r = 0; r < 4; ++r) {
      float M = -3.402823466e38f;
      #pragma unroll
      for (int c = 0; c < 17; ++c) M = fmaxf(M, sv[r][c]);
      M_[r] = M;
    }
    #pragma unroll
    for (int off = 32; off >= 1; off >>= 1) {
      #pragma unroll
      for (int r = 0; r < 4; ++r) M_[r] = fmaxf(M_[r], __shfl_xor(M_[r], off));
    }
    #pragma unroll
    for (int r = 0; r < 4; ++r) {
      float L = 0.f;
      #pragma unroll
      for (int c = 0; c < 17; ++c) L += __expf(sv[r][c] - M_[r]);
      L_[r] = L;
    }
    #pragma unroll
    for (int off = 32; off >= 1; off >>= 1) {
      #pragma unroll
      for (int r = 0; r < 4; ++r) L_[r] += __shfl_xor(L_[r], off);
    }
    #pragma unroll
    for (int r = 0; r < 4; ++r) invL_[r] = 1.0f / L_[r];
  }

  // ---- segment 1 keys + per-lane top-2 init ----
  unsigned kh[4][16];
  #pragma unroll
  for (int r = 0; r < 4; ++r)
    #pragma unroll
    for (int c = 0; c < 16; ++c) kh[r][c] = ordf(sv[r][c]);

  unsigned long long b1_[4], b2_[4];
  unsigned alive_[4];
  #pragma unroll
  for (int r = 0; r < 4; ++r) {
    unsigned long long b1 = 0ull, b2 = 0ull;
    #pragma unroll
    for (int c = 0; c < 16; ++c) {
      const unsigned long long k64 =
          ((unsigned long long)kh[r][c] << 32) | (unsigned)~(unsigned)(c * 64 + lane);
      const unsigned long long mn = (k64 < b1) ? k64 : b1;  // min(b1,k)
      b1 = (k64 > b1) ? k64 : b1;
      b2 = (mn > b2) ? mn : b2;
    }
    b1_[r] = b1; b2_[r] = b2; alive_[r] = 0xFFFFu;
  }

  // ---- segment 1: 16 extraction rounds, 4 rows interleaved ----
  for (int round = 0; round < TOPK; ++round) {
    unsigned long long w0 = b1_[0], w1 = b1_[1], w2 = b1_[2], w3 = b1_[3];
    #pragma unroll
    for (int off = 1; off < 64; off <<= 1) {
      unsigned long long o;
      o = shfl_xor_u64(w0, off); w0 = (o > w0) ? o : w0;
      o = shfl_xor_u64(w1, off); w1 = (o > w1) ? o : w1;
      o = shfl_xor_u64(w2, off); w2 = (o > w2) ? o : w2;
      o = shfl_xor_u64(w3, off); w3 = (o > w3) ? o : w3;
    }
    const unsigned long long ws[4] = {w0, w1, w2, w3};
    #pragma unroll
    for (int r = 0; r < 4; ++r) {
      const unsigned long long w = ws[r];
      const int m = (int)((~(unsigned)w) & 1023u);
      if (lane == round) {
        kept_m[r0 + r][round] = m;
        kept_p[r0 + r][round] = __expf(unordf((unsigned)(w >> 32)) - M_[r]) * invL_[r];
      }
      if ((m & 63) == lane) {          // winner lane bookkeeping
        alive_[r] &= ~(1u << (m >> 6));
        if (b2_[r]) { b1_[r] = b2_[r]; b2_[r] = 0ull; }
        else {
          unsigned long long mx = 0ull;
          #pragma unroll
          for (int c = 0; c < 16; ++c) {
            const unsigned long long k64 =
                ((unsigned long long)kh[r][c] << 32) | (unsigned)~(unsigned)(c * 64 + lane);
            if ((alive_[r] >> c) & 1u) mx = (k64 > mx) ? k64 : mx;
          }
          b1_[r] = mx;
        }
      }
    }
  }

  // ---- segment 2: bitonic sort (descending) of the 64 tail candidates ----
  {
    unsigned long long w_[4];
    #pragma unroll
    for (int r = 0; r < 4; ++r)
      w_[r] = ((unsigned long long)ordf(sv[r][16]) << 32) | (unsigned)~(unsigned)lane;
    #pragma unroll
    for (int k = 2; k <= 64; k <<= 1) {
      #pragma unroll
      for (int j = k >> 1; j >= 1; j >>= 1) {
        const bool tm = (((lane & j) != 0) == ((lane & k) != 0));
        #pragma unroll
        for (int r = 0; r < 4; ++r) {
          const unsigned long long o = shfl_xor_u64(w_[r], j);
          w_[r] = ((o > w_[r]) == tm) ? o : w_[r];
        }
      }
    }
    if (lane < TOPK) {
      #pragma unroll
      for (int r = 0; r < 4; ++r) {
        kept_m[r0 + r][TOPK + lane] = 1024 + (int)((~(unsigned)w_[r]) & 63u);
        kept_p[r0 + r][TOPK + lane] =
            __expf(unordf((unsigned)(w_[r] >> 32)) - M_[r]) * invL_[r];
      }
    }
  }
  __syncthreads();

  #pragma unroll
  for (int rr = 0; rr < 4; ++rr) {
    const int r_loc = wave * 4 + rr;
    const int n = n0 + r_loc;
    float x = 0.f;
    #pragma unroll
    for (int i = 0; i < 32; ++i) {
      const int m = clampi(kept_m[r_loc][i], 0, NN2 - 1);
      const float p = kept_p[r_loc][i];
      x = fmaf(p, V[(size_t)(b * NN2 + m) * (NHEAD * DK) + h * DK + lane], x);
    }
    outx[(size_t)(b * SEQLEN + n) * (NHEAD * DK) + h * DK + lane] = x;
  }
}

// ---------------------------------------------------------------------------
extern "C" void kernel_launch(void* const* d_in, const int* in_sizes, int n_in,
                              void* d_out, int out_size, void* d_ws, size_t ws_size,
                              hipStream_t stream) {
  const float* item    = (const float*)d_in[0];
  const float* intent  = (const float*)d_in[1];
  // d_in[2] = mask: constant all-True -> no-op, skipped
  const int*   b_seq   = (const int*)d_in[3];
  const int*   b_seq2  = (const int*)d_in[4];
  const float* W_item  = (const float*)d_in[5];   // [9][1024][16][64]
  const float* W_int   = (const float*)d_in[6];   // [2][9][1024][16][64]

  if (ws_size < WS_NEED) return;   // clean failure instead of device fault

  char* ws = (char*)d_ws;
  float* qb = (float*)(ws + Q_OFF);
  float* kb = (float*)(ws + K_OFF);
  float* vb = (float*)(ws + V_OFF);
  double* q0d = (double*)(ws + Q0D_OFF);   // aliases V region (used before v-GEMM)
  double* k0dT = (double*)(ws + K0D_OFF);  // transposed [64][T_INT]
  int* cnt       = (int*)(ws + CNT_OFF);
  int* list_item = (int*)(ws + LI_OFF);
  int* list_int  = (int*)(ws + LN_OFF);

  const bool sk = (ws_size >= WS_NEED2);   // split-K only if partials fit
  float* pq = sk ? (float*)(ws + P_OFF + Q_OFF) : qb;
  float* pk = sk ? (float*)(ws + P_OFF + K_OFF) : kb;
  float* pv = sk ? (float*)(ws + P_OFF + V_OFF) : vb;

  float* outx  = (float*)d_out;
  float* out_s = outx + X_OUT_ELEMS;
  float* out_a = out_s + SIDX_ELEMS;

  hipMemsetAsync(cnt, 0, 128, stream);
  bucketize_kernel<<<dim3(9), 256, 0, stream>>>(b_seq, b_seq2, cnt, list_item, list_int);

  // fp64 sidecar: fused head-0 q/k projections (one launch) + 4-row argmax.
  proj_head0_f64_v2<<<dim3(T_ITEM + T_INT), 256, 0, stream>>>(
      item, intent, W_item, W_int, b_seq, b_seq2, q0d, k0dT);
  argmax_f64_v2<<<dim3(T_ITEM / AR), 256, 0, stream>>>(q0d, k0dT, out_s, out_a);

  // fused fp32 q/k/v grouped GEMM (after argmax; v-write aliases sidecar)
  const int klen = sk ? (DMODEL / 2) : DMODEL;
  const int nz   = sk ? 54 : 27;
  gemm_grouped_fused<<<dim3((NHEAD * DK) / GTN, 17, nz), 256, 0, stream>>>(
      item, intent,
      W_item, W_int, W_int + (size_t)NBUCK * DMODEL * (NHEAD * DK),
      list_item, list_int, cnt, qb, kb, vb, pq, pk, pv, klen);
  if (sk) {
    reduce_add<<<dim3(2048), 256, 0, stream>>>(
        (float4*)(ws + Q_OFF), (float4*)(ws + P_OFF), (int)(QKV_BYTES / 16));
  }

  attn_kernel<<<dim3(SEQLEN / 16, NHEAD, BSZ), 256, 0, stream>>>(qb, kb, vb, outx);
}